// Round 6
// baseline (6381.853 us; speedup 1.0000x reference)
//
#include <hip/hip_runtime.h>
#include <hip/hip_bf16.h>

#define BB 64
#define TT 1000
#define DD 16
#define HH 1024
#define OO 8

#define NGRP 16         // batch groups
#define GB   4          // batches per group
#define SJ   64         // j-units per block
#define NJS  16         // blocks per group = HH/SJ
#define NBLK 256        // NGRP * NJS
#define NTH  512

typedef unsigned long long u64;

// ---------------------------------------------------------------------------
// Tier-1 kernel: W pinned in VGPRs via opaque asm loads; th exchanged as
// packed (f32 bits | tag<<32) u64 words -> poll IS the data load.
// Tag protocol: init writes tag 1 to buf0; finalize(t) writes tag t+2 to
// buf (t&1)^1; consumer at step t polls buf t&1 for tag == t+1.
// Replay safety: previous-run residues are tag 1001 (buf0) / 1000 (buf1);
// tag-poll targets are <= 999 except t=999 (target 1000), which is instead
// gated by a flag round (flags memset to 0 every launch) written at t=998.
// Ring WAR safety: every block polls ALL 16 producers each step (8 waves x
// 2), so block X's finalize(t+1) happens-after every block's barrier(t),
// which happens-after their stage-reads(t).
// ---------------------------------------------------------------------------
__global__ __launch_bounds__(NTH, 2) void rnn_coop_tag(
    const float* __restrict__ x,     // [64][1000][16]
    const float* __restrict__ h0,    // [64][1024]
    const float* __restrict__ Wi2h,  // [1024][16]
    const float* Wh2h,               // [1024][1024]
    float* __restrict__ out_h,       // [64][1000][1024]
    u64* TH2,                        // [2][NGRP][GB][HH] packed
    unsigned* flags)                 // [NGRP][NJS][16]  (memset 0 per launch)
{
    __shared__ __align__(16) float THl[8][4][GB][36];   // wave-private stripes
    __shared__ float SC[2][GB][SJ][9];                  // [p][b][j][w]
    __shared__ float XS[2][GB][20];                     // [p][b][d]

    const int tid = threadIdx.x;
    const int w   = tid >> 6;
    const int l   = tid & 63;
    const int bid = blockIdx.x;
    const int bg  = bid & (NGRP - 1);
    const int js  = bid >> 4;         // 0..15

    const int j16 = l & 15;
    const int k4  = l >> 4;           // bits 4-5 -> xor16/xor32 reduce
    const int jbase = js * SJ + j16 * 4;
    const int kbase = w * 128 + k4 * 32;

    // ---- W slice -> VGPRs via opaque asm loads (cannot be rematerialized) --
    float4 w4[4][8];
#pragma unroll
    for (int jj = 0; jj < 4; ++jj) {
        const float* a = &Wh2h[(size_t)(jbase + jj) * HH + kbase];
        asm volatile(
            "global_load_dwordx4 %0, %8, off\n\t"
            "global_load_dwordx4 %1, %8, off offset:16\n\t"
            "global_load_dwordx4 %2, %8, off offset:32\n\t"
            "global_load_dwordx4 %3, %8, off offset:48\n\t"
            "global_load_dwordx4 %4, %8, off offset:64\n\t"
            "global_load_dwordx4 %5, %8, off offset:80\n\t"
            "global_load_dwordx4 %6, %8, off offset:96\n\t"
            "global_load_dwordx4 %7, %8, off offset:112\n\t"
            "s_waitcnt vmcnt(0)"
            : "=&v"(w4[jj][0]), "=&v"(w4[jj][1]), "=&v"(w4[jj][2]), "=&v"(w4[jj][3]),
              "=&v"(w4[jj][4]), "=&v"(w4[jj][5]), "=&v"(w4[jj][6]), "=&v"(w4[jj][7])
            : "v"(a));
    }

    // ---- finalize role: tid<256 owns (fb = tid>>6, fj = tid&63) ----
    const int fb = tid >> 6, fj = tid & 63;
    float h = 0.f;
    float wi[DD];
    if (tid < 256) {
        h = h0[(size_t)(bg * GB + fb) * HH + js * SJ + fj];
#pragma unroll
        for (int d = 0; d < DD; ++d) wi[d] = Wi2h[(js * SJ + fj) * DD + d];
        u64 pk = ((u64)1u << 32) | (u64)__float_as_uint(tanhf(h));
        __hip_atomic_store(&TH2[((size_t)(0 * NGRP + bg) * GB + fb) * HH + js * SJ + fj],
                           pk, __ATOMIC_RELAXED, __HIP_MEMORY_SCOPE_AGENT);
    }

    for (int t = 0; t < TT; ++t) {
        const int p = t & 1;
        const unsigned tg = (unsigned)(t + 1);
        const int sb = l >> 4, sq = l & 15;

        // ---- x prefetch (wave 0), latency hidden under the poll ----
        if (w == 0 && l < 16) {
            int xb = l >> 2, dq = (l & 3) * 4;
            float4 v = *(const float4*)&x[((size_t)(bg * GB + xb) * TT + t) * DD + dq];
            *(float4*)&XS[p][xb][dq] = v;
        }

        // ---- poll-load the wave's 128-k stripe (8 packed pairs / lane) ----
        const u64* base = TH2 + ((size_t)(p * NGRP + bg) * GB + sb) * HH
                              + w * 128 + sq * 8;
        uint4 A, B, C, D;
        if (t == TT - 1) {
            // final step: gate on memset-fresh flags (tag 1000 aliases prev run)
            const unsigned* fa = flags +
                ((size_t)bg * NJS + (2 * w + (l >> 2))) * 16 + (l & 3);
            for (;;) {
                unsigned v = 1u;
                if (l < 8)
                    v = __hip_atomic_load(fa, __ATOMIC_RELAXED, __HIP_MEMORY_SCOPE_AGENT);
                if (__all((int)(v != 0))) break;
                __builtin_amdgcn_s_sleep(1);
            }
        }
        for (;;) {
            asm volatile(
                "global_load_dwordx4 %0, %4, off sc0 sc1\n\t"
                "global_load_dwordx4 %1, %4, off offset:16 sc0 sc1\n\t"
                "global_load_dwordx4 %2, %4, off offset:32 sc0 sc1\n\t"
                "global_load_dwordx4 %3, %4, off offset:48 sc0 sc1\n\t"
                "s_waitcnt vmcnt(0)"
                : "=&v"(A), "=&v"(B), "=&v"(C), "=&v"(D)
                : "v"(base) : "memory");
            if (t == TT - 1) break;   // flag-gated, tags guaranteed fresh
            unsigned bad = (A.y ^ tg) | (A.w ^ tg) | (B.y ^ tg) | (B.w ^ tg) |
                           (C.y ^ tg) | (C.w ^ tg) | (D.y ^ tg) | (D.w ^ tg);
            if (__all((int)(bad == 0))) break;
            __builtin_amdgcn_s_sleep(1);
        }

        // ---- unpack -> LDS (quad-swizzled, same layout as compute reads) ----
        {
            int Q0 = sq * 2, Q1 = sq * 2 + 1;
            int k40 = Q0 >> 3, kk0 = (Q0 & 7) ^ k40;
            int k41 = Q1 >> 3, kk1 = (Q1 & 7) ^ k41;
            float4 f0 = make_float4(__uint_as_float(A.x), __uint_as_float(A.z),
                                    __uint_as_float(B.x), __uint_as_float(B.z));
            float4 f1 = make_float4(__uint_as_float(C.x), __uint_as_float(C.z),
                                    __uint_as_float(D.x), __uint_as_float(D.z));
            *(float4*)&THl[w][k40][sb][kk0 * 4] = f0;
            *(float4*)&THl[w][k41][sb][kk1 * 4] = f1;
        }
        asm volatile("s_waitcnt lgkmcnt(0)" ::: "memory");
        __builtin_amdgcn_sched_barrier(0);

        // ---- compute: acc[jj][m] over lane's 32-k slice (512 FMA) ----
        float acc[4][4];
#pragma unroll
        for (int jj = 0; jj < 4; ++jj)
#pragma unroll
            for (int m = 0; m < 4; ++m) acc[jj][m] = 0.f;
#pragma unroll
        for (int kq = 0; kq < 8; ++kq) {
            const int kks = (kq ^ k4) * 4;
#pragma unroll
            for (int m = 0; m < 4; ++m) {
                float4 tv = *(const float4*)&THl[w][k4][m][kks];
#pragma unroll
                for (int jj = 0; jj < 4; ++jj) {
                    acc[jj][m] += w4[jj][kq].x * tv.x;
                    acc[jj][m] += w4[jj][kq].y * tv.y;
                    acc[jj][m] += w4[jj][kq].z * tv.z;
                    acc[jj][m] += w4[jj][kq].w * tv.w;
                }
            }
        }

        // ---- reduce over k4 (xor16, xor32), publish per-wave partials ----
#pragma unroll
        for (int jj = 0; jj < 4; ++jj)
#pragma unroll
            for (int m = 0; m < 4; ++m) {
                float a = acc[jj][m];
                a += __shfl_xor(a, 16, 64);
                a += __shfl_xor(a, 32, 64);
                acc[jj][m] = a;
            }
        if (k4 == 0) {
#pragma unroll
            for (int m = 0; m < 4; ++m)
#pragma unroll
                for (int jj = 0; jj < 4; ++jj)
                    SC[p][m][j16 * 4 + jj][w] = acc[jj][m];
        }

        __syncthreads();   // the ONE per-step block barrier

        // ---- finalize: h update, packed publish (fire & forget), out_h ----
        if (tid < 256) {
            float z = 0.f;
#pragma unroll
            for (int ww = 0; ww < 8; ++ww) z += SC[p][fb][fj][ww];
            float xp = 0.f;
#pragma unroll
            for (int d = 0; d < DD; ++d) xp += wi[d] * XS[p][fb][d];
            h = 0.9f * h + 0.1f * (z + xp);
            float th = tanhf(h);
            u64 pk = ((u64)(unsigned)(t + 2) << 32) | (u64)__float_as_uint(th);
            __hip_atomic_store(
                &TH2[((size_t)((p ^ 1) * NGRP + bg) * GB + fb) * HH + js * SJ + fj],
                pk, __ATOMIC_RELAXED, __HIP_MEMORY_SCOPE_AGENT);
            if (t == TT - 2) {          // arm the final-step gate
                asm volatile("s_waitcnt vmcnt(0)" ::: "memory");
                if (l == 0)
                    __hip_atomic_store(&flags[((size_t)bg * NJS + js) * 16 + fb],
                                       1u, __ATOMIC_RELAXED, __HIP_MEMORY_SCOPE_AGENT);
            }
            out_h[((size_t)(bg * GB + fb) * TT + t) * HH + js * SJ + fj] = h;
        }
    }
}

// ---------------------------------------------------------------------------
// Tier-2 kernel: round-5 proven flag+float exchange (smaller ws footprint).
// ---------------------------------------------------------------------------
__global__ __launch_bounds__(NTH, 2) void rnn_coop_flag(
    const float* __restrict__ x, const float* __restrict__ h0,
    const float* __restrict__ Wi2h, const float* Wh2h,
    float* __restrict__ out_h, float* TH, unsigned* flags)
{
    __shared__ __align__(16) float THl[8][4][GB][36];
    __shared__ float SC[2][GB][SJ][9];
    __shared__ float XS[2][GB][20];

    const int tid = threadIdx.x;
    const int w   = tid >> 6;
    const int l   = tid & 63;
    const int bid = blockIdx.x;
    const int bg  = bid & (NGRP - 1);
    const int js  = bid >> 4;

    const int j16 = l & 15;
    const int k4  = l >> 4;
    const int jbase = js * SJ + j16 * 4;
    const int kbase = w * 128 + k4 * 32;

    float4 w4[4][8];
#pragma unroll
    for (int jj = 0; jj < 4; ++jj)
#pragma unroll
        for (int kq = 0; kq < 8; ++kq)
            w4[jj][kq] = *(const float4*)&Wh2h[(size_t)(jbase + jj) * HH + kbase + kq * 4];
#pragma unroll
    for (int jj = 0; jj < 4; ++jj)
#pragma unroll
        for (int kq = 0; kq < 8; ++kq)
            asm volatile("" : "+v"(w4[jj][kq].x), "+v"(w4[jj][kq].y),
                             "+v"(w4[jj][kq].z), "+v"(w4[jj][kq].w));

    const int fb = tid >> 6, fj = tid & 63;
    float h = 0.f;
    float wi[DD];
    if (tid < 256) {
        h = h0[(size_t)(bg * GB + fb) * HH + js * SJ + fj];
#pragma unroll
        for (int d = 0; d < DD; ++d) wi[d] = Wi2h[(js * SJ + fj) * DD + d];
        float th0 = tanhf(h);
        __hip_atomic_store(&TH[((size_t)(0 * NGRP + bg) * GB + fb) * HH + js * SJ + fj],
                           th0, __ATOMIC_RELAXED, __HIP_MEMORY_SCOPE_AGENT);
        asm volatile("s_waitcnt vmcnt(0)" ::: "memory");
        if (l == 0)
            __hip_atomic_store(&flags[((size_t)(0 * NGRP + bg) * NJS + js) * 16 + fb],
                               1u, __ATOMIC_RELAXED, __HIP_MEMORY_SCOPE_AGENT);
    }

    for (int t = 0; t < TT; ++t) {
        const int p = t & 1;
        {
            const unsigned target = (unsigned)(t + 1);
            const unsigned* fa = flags +
                ((size_t)(p * NGRP + bg) * NJS + (2 * w + (l >> 2))) * 16 + (l & 3);
            for (;;) {
                unsigned v = target;
                if (l < 8)
                    v = __hip_atomic_load(fa, __ATOMIC_RELAXED, __HIP_MEMORY_SCOPE_AGENT);
                if (__all((int)(v >= target))) break;
                __builtin_amdgcn_s_sleep(1);
            }
        }
        {
            const int sb = l >> 4, sq = l & 15;
            const float* base = TH + ((size_t)(p * NGRP + bg) * GB + sb) * HH + w * 128;
            const float* a0 = base + sq * 4;
            const float* a1 = base + (sq + 16) * 4;
            float4 v0, v1;
            asm volatile("global_load_dwordx4 %0, %2, off sc0 sc1\n\t"
                         "global_load_dwordx4 %1, %3, off sc0 sc1\n\t"
                         "s_waitcnt vmcnt(0)"
                         : "=&v"(v0), "=&v"(v1)
                         : "v"(a0), "v"(a1)
                         : "memory");
            int k40 = sq >> 3,        kk0 = (sq & 7) ^ k40;
            int k41 = (sq + 16) >> 3, kk1 = (sq & 7) ^ k41;
            *(float4*)&THl[w][k40][sb][kk0 * 4] = v0;
            *(float4*)&THl[w][k41][sb][kk1 * 4] = v1;
        }
        if (w == 0 && l < 16) {
            int sb2 = l >> 2, dq = (l & 3) * 4;
            float4 v = *(const float4*)&x[((size_t)(bg * GB + sb2) * TT + t) * DD + dq];
            *(float4*)&XS[p][sb2][dq] = v;
        }
        asm volatile("s_waitcnt lgkmcnt(0)" ::: "memory");
        __builtin_amdgcn_sched_barrier(0);

        float acc[4][4];
#pragma unroll
        for (int jj = 0; jj < 4; ++jj)
#pragma unroll
            for (int m = 0; m < 4; ++m) acc[jj][m] = 0.f;
#pragma unroll
        for (int kq = 0; kq < 8; ++kq) {
            const int kks = (kq ^ k4) * 4;
#pragma unroll
            for (int m = 0; m < 4; ++m) {
                float4 tv = *(const float4*)&THl[w][k4][m][kks];
#pragma unroll
                for (int jj = 0; jj < 4; ++jj) {
                    acc[jj][m] += w4[jj][kq].x * tv.x;
                    acc[jj][m] += w4[jj][kq].y * tv.y;
                    acc[jj][m] += w4[jj][kq].z * tv.z;
                    acc[jj][m] += w4[jj][kq].w * tv.w;
                }
            }
        }
#pragma unroll
        for (int jj = 0; jj < 4; ++jj)
#pragma unroll
            for (int m = 0; m < 4; ++m) {
                float a = acc[jj][m];
                a += __shfl_xor(a, 16, 64);
                a += __shfl_xor(a, 32, 64);
                acc[jj][m] = a;
            }
        if (k4 == 0) {
#pragma unroll
            for (int m = 0; m < 4; ++m)
#pragma unroll
                for (int jj = 0; jj < 4; ++jj)
                    SC[p][m][j16 * 4 + jj][w] = acc[jj][m];
        }
        __syncthreads();
        if (tid < 256) {
            float z = 0.f;
#pragma unroll
            for (int ww = 0; ww < 8; ++ww) z += SC[p][fb][fj][ww];
            float xp = 0.f;
#pragma unroll
            for (int d = 0; d < DD; ++d) xp += wi[d] * XS[p][fb][d];
            h = 0.9f * h + 0.1f * (z + xp);
            float th = tanhf(h);
            __hip_atomic_store(
                &TH[((size_t)((p ^ 1) * NGRP + bg) * GB + fb) * HH + js * SJ + fj],
                th, __ATOMIC_RELAXED, __HIP_MEMORY_SCOPE_AGENT);
            asm volatile("s_waitcnt vmcnt(0)" ::: "memory");
            if (l == 0 && t + 1 < TT)
                __hip_atomic_store(
                    &flags[((size_t)((p ^ 1) * NGRP + bg) * NJS + js) * 16 + fb],
                    (unsigned)(t + 2), __ATOMIC_RELAXED, __HIP_MEMORY_SCOPE_AGENT);
            out_h[((size_t)(bg * GB + fb) * TT + t) * HH + js * SJ + fj] = h;
        }
    }
}

// ---------------------------------------------------------------------------
// h2o output kernel: out[b][t][o] = sum_j tanh(h[b][t][j]) * Wh2o[o][j]
// ---------------------------------------------------------------------------
__global__ __launch_bounds__(256) void h2o_kernel(
    const float* __restrict__ hs, const float* __restrict__ Wh2o,
    float* __restrict__ out_o)
{
    __shared__ float Wl[OO * HH];
    for (int i = threadIdx.x; i < OO * HH; i += 256) Wl[i] = Wh2o[i];
    __syncthreads();

    const int w = threadIdx.x >> 6, l = threadIdx.x & 63;
    const size_t nrows = (size_t)BB * TT;
    for (size_t row = (size_t)blockIdx.x * 4 + w; row < nrows; row += (size_t)gridDim.x * 4) {
        const float* hr = hs + row * HH;
        float po[OO] = {0.f};
#pragma unroll
        for (int i = 0; i < 16; ++i) {
            int j = l + 64 * i;
            float th = tanhf(hr[j]);
#pragma unroll
            for (int o = 0; o < OO; ++o) po[o] += th * Wl[o * HH + j];
        }
#pragma unroll
        for (int s = 32; s; s >>= 1)
#pragma unroll
            for (int o = 0; o < OO; ++o) po[o] += __shfl_down(po[o], s, 64);
        if (l == 0) {
#pragma unroll
            for (int o = 0; o < OO; ++o) out_o[row * OO + o] = po[o];
        }
    }
}

// ---------------------------------------------------------------------------
// Tier-3 fallback (round-1 style, no workspace needed).
// ---------------------------------------------------------------------------
__global__ __launch_bounds__(512) void rnn_fallback(
    const float* __restrict__ x, const float* __restrict__ h0,
    const float* __restrict__ Wi2h, const float* __restrict__ W,
    const float* __restrict__ Wh2o, float* __restrict__ out_o,
    float* __restrict__ out_h)
{
    const int b = blockIdx.x, t0 = threadIdx.x, j0 = 2 * t0;
    const int wave = t0 >> 6, lane = t0 & 63;
    __shared__ float th[HH];
    __shared__ float xs[DD];
    __shared__ float ored[8][OO];
    float wi[2][DD];
#pragma unroll
    for (int d = 0; d < DD; ++d) {
        wi[0][d] = Wi2h[j0 * DD + d];
        wi[1][d] = Wi2h[(j0 + 1) * DD + d];
    }
    float wo[2][OO];
#pragma unroll
    for (int o = 0; o < OO; ++o) {
        wo[0][o] = Wh2o[o * HH + j0];
        wo[1][o] = Wh2o[o * HH + j0 + 1];
    }
    float h[2] = { h0[b * HH + j0], h0[b * HH + j0 + 1] };
    th[j0] = tanhf(h[0]); th[j0 + 1] = tanhf(h[1]);
    if (t0 < DD) xs[t0] = x[(size_t)(b * TT) * DD + t0];
    __syncthreads();
    for (int t = 0; t < TT; ++t) {
        float a0 = 0.f, a1 = 0.f;
        const float* r0 = W + (size_t)j0 * HH;
        const float* r1 = W + (size_t)(j0 + 1) * HH;
#pragma unroll 4
        for (int k = 0; k < HH; k += 4) {
            float4 t4 = *(const float4*)&th[k];
            float4 wA = *(const float4*)(r0 + k);
            float4 wB = *(const float4*)(r1 + k);
            a0 += t4.x * wA.x + t4.y * wA.y + t4.z * wA.z + t4.w * wA.w;
            a1 += t4.x * wB.x + t4.y * wB.y + t4.z * wB.z + t4.w * wB.w;
        }
        float xp0 = 0.f, xp1 = 0.f;
#pragma unroll
        for (int d = 0; d < DD; ++d) { xp0 += xs[d] * wi[0][d]; xp1 += xs[d] * wi[1][d]; }
        h[0] = 0.9f * h[0] + 0.1f * (a0 + xp0);
        h[1] = 0.9f * h[1] + 0.1f * (a1 + xp1);
        float th0 = tanhf(h[0]), th1 = tanhf(h[1]);
        *(float2*)&out_h[((size_t)b * TT + t) * HH + j0] = make_float2(h[0], h[1]);
        float po[OO];
#pragma unroll
        for (int o = 0; o < OO; ++o) po[o] = th0 * wo[0][o] + th1 * wo[1][o];
#pragma unroll
        for (int s = 32; s; s >>= 1)
#pragma unroll
            for (int o = 0; o < OO; ++o) po[o] += __shfl_down(po[o], s, 64);
        __syncthreads();
        if (lane == 0)
#pragma unroll
            for (int o = 0; o < OO; ++o) ored[wave][o] = po[o];
        th[j0] = th0; th[j0 + 1] = th1;
        if (t0 < DD && t + 1 < TT) xs[t0] = x[(size_t)(b * TT + t + 1) * DD + t0];
        __syncthreads();
        if (t0 < OO) {
            float s = 0.f;
#pragma unroll
            for (int ww = 0; ww < 8; ++ww) s += ored[ww][t0];
            out_o[((size_t)b * TT + t) * OO + t0] = s;
        }
    }
}

extern "C" void kernel_launch(void* const* d_in, const int* in_sizes, int n_in,
                              void* d_out, int out_size, void* d_ws, size_t ws_size,
                              hipStream_t stream) {
    const float* x    = (const float*)d_in[0];
    const float* h0   = (const float*)d_in[1];
    const float* Wi2h = (const float*)d_in[2];
    const float* Wh2h = (const float*)d_in[3];
    const float* Wh2o = (const float*)d_in[4];

    float* out_o = (float*)d_out;                    // [64][1000][8]
    float* out_h = out_o + (size_t)BB * TT * OO;     // [64][1000][1024]

    const size_t th2_bytes  = (size_t)2 * NGRP * GB * HH * sizeof(u64);       // 1 MB
    const size_t flg2_bytes = (size_t)NGRP * NJS * 16 * sizeof(unsigned);     // 16 KB
    const size_t th5_bytes  = (size_t)2 * NGRP * GB * HH * sizeof(float);     // 512 KB
    const size_t flg5_bytes = (size_t)2 * NGRP * NJS * 16 * sizeof(unsigned); // 32 KB

    if (ws_size >= th2_bytes + flg2_bytes) {
        u64*      TH2 = (u64*)d_ws;
        unsigned* flg = (unsigned*)((char*)d_ws + th2_bytes);
        hipMemsetAsync(flg, 0, flg2_bytes, stream);
        rnn_coop_tag<<<NBLK, NTH, 0, stream>>>(x, h0, Wi2h, Wh2h, out_h, TH2, flg);
        h2o_kernel<<<2048, 256, 0, stream>>>(out_h, Wh2o, out_o);
    } else if (ws_size >= th5_bytes + flg5_bytes) {
        float*    TH  = (float*)d_ws;
        unsigned* flg = (unsigned*)((char*)d_ws + th5_bytes);
        hipMemsetAsync(flg, 0, flg5_bytes, stream);
        rnn_coop_flag<<<NBLK, NTH, 0, stream>>>(x, h0, Wi2h, Wh2h, out_h, TH, flg);
        h2o_kernel<<<2048, 256, 0, stream>>>(out_h, Wh2o, out_o);
    } else {
        rnn_fallback<<<BB, 512, 0, stream>>>(x, h0, Wi2h, Wh2h, Wh2o, out_o, out_h);
    }
}

// Round 7
// 5007.137 us; speedup vs baseline: 1.2746x; 1.2746x over previous
//
#include <hip/hip_runtime.h>
#include <hip/hip_bf16.h>

#define BB 64
#define TT 1000
#define DD 16
#define HH 1024
#define OO 8

#define NGRP 16         // batch groups
#define GB   4          // batches per group
#define SJ   64         // j-units per block
#define NJS  16         // blocks per group = HH/SJ
#define NBLK 256        // NGRP * NJS
#define NTH  512

// ---------------------------------------------------------------------------
// Persistent cooperative RNN. Block (bg, js): batches [bg*4,+4), units
// [js*64,+64). W slice (64x1024) pinned in VGPRs: loaded via opaque asm
// (not rematerializable) under __launch_bounds__(512,1) -> 256-VGPR budget,
// so the allocator keeps all 128 W floats resident (check: VGPR_Count>160).
// Wave w owns k-stripe [w*128,+128); lane = j16 (l&15) x k4 (l>>4):
// per lane 4j x 4b x 32k = 512 FMA/step.
// th exchange (round-5 proven): TH[2][NGRP][GB][HH] relaxed-agent stores +
// per-(js,wave) flag lines; consumers poll 8 lanes then LLC-direct
// sc0 sc1 dwordx4 stripe loads, no fences. Ring WAR safety: every block
// polls all 16 producers each step, so finalize(t+1) happens-after all
// blocks' stage-reads(t). One __syncthreads per step.
// ---------------------------------------------------------------------------
__global__ __launch_bounds__(NTH, 1) void rnn_coop(
    const float* __restrict__ x,     // [64][1000][16]
    const float* __restrict__ h0,    // [64][1024]
    const float* __restrict__ Wi2h,  // [1024][16]
    const float* Wh2h,               // [1024][1024]
    float* __restrict__ out_h,       // [64][1000][1024]
    float* TH,                       // [2][NGRP][GB][HH]
    unsigned* flags)                 // [2][NGRP][NJS][16]
{
    __shared__ __align__(16) float THl[8][4][GB][36];   // wave-private stripes
    __shared__ float SC[2][GB][SJ][9];                  // [p][b][j][w]
    __shared__ float XS[2][GB][20];                     // [p][b][d]

    const int tid = threadIdx.x;
    const int w   = tid >> 6;
    const int l   = tid & 63;
    const int bid = blockIdx.x;
    const int bg  = bid & (NGRP - 1);
    const int js  = bid >> 4;         // 0..15

    const int j16 = l & 15;
    const int k4  = l >> 4;           // bits 4-5 -> xor16/xor32 reduce
    const int jbase = js * SJ + j16 * 4;
    const int kbase = w * 128 + k4 * 32;

    // ---- W slice -> VGPRs via opaque asm loads (cannot rematerialize) ----
    float4 w4[4][8];
#pragma unroll
    for (int jj = 0; jj < 4; ++jj) {
        const float* a = &Wh2h[(size_t)(jbase + jj) * HH + kbase];
        asm volatile(
            "global_load_dwordx4 %0, %8, off\n\t"
            "global_load_dwordx4 %1, %8, off offset:16\n\t"
            "global_load_dwordx4 %2, %8, off offset:32\n\t"
            "global_load_dwordx4 %3, %8, off offset:48\n\t"
            "global_load_dwordx4 %4, %8, off offset:64\n\t"
            "global_load_dwordx4 %5, %8, off offset:80\n\t"
            "global_load_dwordx4 %6, %8, off offset:96\n\t"
            "global_load_dwordx4 %7, %8, off offset:112\n\t"
            "s_waitcnt vmcnt(0)"
            : "=&v"(w4[jj][0]), "=&v"(w4[jj][1]), "=&v"(w4[jj][2]), "=&v"(w4[jj][3]),
              "=&v"(w4[jj][4]), "=&v"(w4[jj][5]), "=&v"(w4[jj][6]), "=&v"(w4[jj][7])
            : "v"(a));
    }

    // ---- finalize role: tid<256 owns (fb = tid>>6, fj = tid&63) ----
    const int fb = tid >> 6, fj = tid & 63;
    float h = 0.f;
    float wi[DD];
    if (tid < 256) {
        h = h0[(size_t)(bg * GB + fb) * HH + js * SJ + fj];
#pragma unroll
        for (int d = 0; d < DD; ++d) wi[d] = Wi2h[(js * SJ + fj) * DD + d];
        float th0 = tanhf(h);
        __hip_atomic_store(&TH[((size_t)(0 * NGRP + bg) * GB + fb) * HH + js * SJ + fj],
                           th0, __ATOMIC_RELAXED, __HIP_MEMORY_SCOPE_AGENT);
        asm volatile("s_waitcnt vmcnt(0)" ::: "memory");
        if (l == 0)
            __hip_atomic_store(&flags[((size_t)(0 * NGRP + bg) * NJS + js) * 16 + fb],
                               1u, __ATOMIC_RELAXED, __HIP_MEMORY_SCOPE_AGENT);
    }

    for (int t = 0; t < TT; ++t) {
        const int p = t & 1;

        // ---- poll: wave w needs producers js' in {2w, 2w+1} (8 lanes) ----
        {
            const unsigned target = (unsigned)(t + 1);
            const unsigned* fa = flags +
                ((size_t)(p * NGRP + bg) * NJS + (2 * w + (l >> 2))) * 16 + (l & 3);
            for (;;) {
                unsigned v = target;
                if (l < 8)
                    v = __hip_atomic_load(fa, __ATOMIC_RELAXED, __HIP_MEMORY_SCOPE_AGENT);
                if (__all((int)(v >= target))) break;
                __builtin_amdgcn_s_sleep(1);
            }
        }

        // ---- stage wave's 128-k stripe: LLC-direct sc1 loads, no fence ----
        {
            const int sb = l >> 4, sq = l & 15;
            const float* base = TH + ((size_t)(p * NGRP + bg) * GB + sb) * HH + w * 128;
            const float* a0 = base + sq * 4;          // quad Q = sq
            const float* a1 = base + (sq + 16) * 4;   // quad Q = sq+16
            float4 v0, v1;
            asm volatile("global_load_dwordx4 %0, %2, off sc0 sc1\n\t"
                         "global_load_dwordx4 %1, %3, off sc0 sc1\n\t"
                         "s_waitcnt vmcnt(0)"
                         : "=&v"(v0), "=&v"(v1)
                         : "v"(a0), "v"(a1)
                         : "memory");
            int k40 = sq >> 3,        kk0 = (sq & 7) ^ k40;
            int k41 = (sq + 16) >> 3, kk1 = (sq & 7) ^ k41;   // (Q1&7)==sq&7
            *(float4*)&THl[w][k40][sb][kk0 * 4] = v0;
            *(float4*)&THl[w][k41][sb][kk1 * 4] = v1;
        }
        if (w == 0 && l < 16) {   // stage x tile (plain loads, L2-warm)
            int sb2 = l >> 2, dq = (l & 3) * 4;
            float4 v = *(const float4*)&x[((size_t)(bg * GB + sb2) * TT + t) * DD + dq];
            *(float4*)&XS[p][sb2][dq] = v;
        }
        asm volatile("s_waitcnt lgkmcnt(0)" ::: "memory");
        __builtin_amdgcn_sched_barrier(0);

        // ---- compute: acc[jj][m] over lane's 32-k slice (512 FMA) ----
        float acc[4][4];
#pragma unroll
        for (int jj = 0; jj < 4; ++jj)
#pragma unroll
            for (int m = 0; m < 4; ++m) acc[jj][m] = 0.f;
#pragma unroll
        for (int kq = 0; kq < 8; ++kq) {
            const int kks = (kq ^ k4) * 4;
#pragma unroll
            for (int m = 0; m < 4; ++m) {
                float4 tv = *(const float4*)&THl[w][k4][m][kks];
#pragma unroll
                for (int jj = 0; jj < 4; ++jj) {
                    acc[jj][m] += w4[jj][kq].x * tv.x;
                    acc[jj][m] += w4[jj][kq].y * tv.y;
                    acc[jj][m] += w4[jj][kq].z * tv.z;
                    acc[jj][m] += w4[jj][kq].w * tv.w;
                }
            }
        }

        // ---- reduce over k4 (xor16, xor32), publish per-wave partials ----
#pragma unroll
        for (int jj = 0; jj < 4; ++jj)
#pragma unroll
            for (int m = 0; m < 4; ++m) {
                float a = acc[jj][m];
                a += __shfl_xor(a, 16, 64);
                a += __shfl_xor(a, 32, 64);
                acc[jj][m] = a;
            }
        if (k4 == 0) {
#pragma unroll
            for (int m = 0; m < 4; ++m)
#pragma unroll
                for (int jj = 0; jj < 4; ++jj)
                    SC[p][m][j16 * 4 + jj][w] = acc[jj][m];
        }

        __syncthreads();   // the ONE per-step block barrier

        // ---- finalize: h update, TH+flag publish, out_h ----
        if (tid < 256) {
            float z = 0.f;
#pragma unroll
            for (int ww = 0; ww < 8; ++ww) z += SC[p][fb][fj][ww];
            float xp = 0.f;
#pragma unroll
            for (int d = 0; d < DD; ++d) xp += wi[d] * XS[p][fb][d];
            h = 0.9f * h + 0.1f * (z + xp);
            float th = tanhf(h);
            __hip_atomic_store(
                &TH[((size_t)((p ^ 1) * NGRP + bg) * GB + fb) * HH + js * SJ + fj],
                th, __ATOMIC_RELAXED, __HIP_MEMORY_SCOPE_AGENT);
            asm volatile("s_waitcnt vmcnt(0)" ::: "memory");
            if (l == 0 && t + 1 < TT)
                __hip_atomic_store(
                    &flags[((size_t)((p ^ 1) * NGRP + bg) * NJS + js) * 16 + fb],
                    (unsigned)(t + 2), __ATOMIC_RELAXED, __HIP_MEMORY_SCOPE_AGENT);
            out_h[((size_t)(bg * GB + fb) * TT + t) * HH + js * SJ + fj] = h;
        }
    }
}

// ---------------------------------------------------------------------------
// h2o output kernel: out[b][t][o] = sum_j tanh(h[b][t][j]) * Wh2o[o][j]
// ---------------------------------------------------------------------------
__global__ __launch_bounds__(256) void h2o_kernel(
    const float* __restrict__ hs, const float* __restrict__ Wh2o,
    float* __restrict__ out_o)
{
    __shared__ float Wl[OO * HH];
    for (int i = threadIdx.x; i < OO * HH; i += 256) Wl[i] = Wh2o[i];
    __syncthreads();

    const int w = threadIdx.x >> 6, l = threadIdx.x & 63;
    const size_t nrows = (size_t)BB * TT;
    for (size_t row = (size_t)blockIdx.x * 4 + w; row < nrows; row += (size_t)gridDim.x * 4) {
        const float* hr = hs + row * HH;
        float po[OO] = {0.f};
#pragma unroll
        for (int i = 0; i < 16; ++i) {
            int j = l + 64 * i;
            float th = tanhf(hr[j]);
#pragma unroll
            for (int o = 0; o < OO; ++o) po[o] += th * Wl[o * HH + j];
        }
#pragma unroll
        for (int s = 32; s; s >>= 1)
#pragma unroll
            for (int o = 0; o < OO; ++o) po[o] += __shfl_down(po[o], s, 64);
        if (l == 0) {
#pragma unroll
            for (int o = 0; o < OO; ++o) out_o[row * OO + o] = po[o];
        }
    }
}

// ---------------------------------------------------------------------------
// Fallback (round-1 style, no workspace needed).
// ---------------------------------------------------------------------------
__global__ __launch_bounds__(512) void rnn_fallback(
    const float* __restrict__ x, const float* __restrict__ h0,
    const float* __restrict__ Wi2h, const float* __restrict__ W,
    const float* __restrict__ Wh2o, float* __restrict__ out_o,
    float* __restrict__ out_h)
{
    const int b = blockIdx.x, t0 = threadIdx.x, j0 = 2 * t0;
    const int wave = t0 >> 6, lane = t0 & 63;
    __shared__ float th[HH];
    __shared__ float xs[DD];
    __shared__ float ored[8][OO];
    float wi[2][DD];
#pragma unroll
    for (int d = 0; d < DD; ++d) {
        wi[0][d] = Wi2h[j0 * DD + d];
        wi[1][d] = Wi2h[(j0 + 1) * DD + d];
    }
    float wo[2][OO];
#pragma unroll
    for (int o = 0; o < OO; ++o) {
        wo[0][o] = Wh2o[o * HH + j0];
        wo[1][o] = Wh2o[o * HH + j0 + 1];
    }
    float h[2] = { h0[b * HH + j0], h0[b * HH + j0 + 1] };
    th[j0] = tanhf(h[0]); th[j0 + 1] = tanhf(h[1]);
    if (t0 < DD) xs[t0] = x[(size_t)(b * TT) * DD + t0];
    __syncthreads();
    for (int t = 0; t < TT; ++t) {
        float a0 = 0.f, a1 = 0.f;
        const float* r0 = W + (size_t)j0 * HH;
        const float* r1 = W + (size_t)(j0 + 1) * HH;
#pragma unroll 4
        for (int k = 0; k < HH; k += 4) {
            float4 t4 = *(const float4*)&th[k];
            float4 wA = *(const float4*)(r0 + k);
            float4 wB = *(const float4*)(r1 + k);
            a0 += t4.x * wA.x + t4.y * wA.y + t4.z * wA.z + t4.w * wA.w;
            a1 += t4.x * wB.x + t4.y * wB.y + t4.z * wB.z + t4.w * wB.w;
        }
        float xp0 = 0.f, xp1 = 0.f;
#pragma unroll
        for (int d = 0; d < DD; ++d) { xp0 += xs[d] * wi[0][d]; xp1 += xs[d] * wi[1][d]; }
        h[0] = 0.9f * h[0] + 0.1f * (a0 + xp0);
        h[1] = 0.9f * h[1] + 0.1f * (a1 + xp1);
        float th0 = tanhf(h[0]), th1 = tanhf(h[1]);
        *(float2*)&out_h[((size_t)b * TT + t) * HH + j0] = make_float2(h[0], h[1]);
        float po[OO];
#pragma unroll
        for (int o = 0; o < OO; ++o) po[o] = th0 * wo[0][o] + th1 * wo[1][o];
#pragma unroll
        for (int s = 32; s; s >>= 1)
#pragma unroll
            for (int o = 0; o < OO; ++o) po[o] += __shfl_down(po[o], s, 64);
        __syncthreads();
        if (lane == 0)
#pragma unroll
            for (int o = 0; o < OO; ++o) ored[wave][o] = po[o];
        th[j0] = th0; th[j0 + 1] = th1;
        if (t0 < DD && t + 1 < TT) xs[t0] = x[(size_t)(b * TT + t + 1) * DD + t0];
        __syncthreads();
        if (t0 < OO) {
            float s = 0.f;
#pragma unroll
            for (int ww = 0; ww < 8; ++ww) s += ored[ww][t0];
            out_o[((size_t)b * TT + t) * OO + t0] = s;
        }
    }
}

extern "C" void kernel_launch(void* const* d_in, const int* in_sizes, int n_in,
                              void* d_out, int out_size, void* d_ws, size_t ws_size,
                              hipStream_t stream) {
    const float* x    = (const float*)d_in[0];
    const float* h0   = (const float*)d_in[1];
    const float* Wi2h = (const float*)d_in[2];
    const float* Wh2h = (const float*)d_in[3];
    const float* Wh2o = (const float*)d_in[4];

    float* out_o = (float*)d_out;                    // [64][1000][8]
    float* out_h = out_o + (size_t)BB * TT * OO;     // [64][1000][1024]

    const size_t th_bytes   = (size_t)2 * NGRP * GB * HH * sizeof(float);      // 512 KB
    const size_t flag_bytes = (size_t)2 * NGRP * NJS * 16 * sizeof(unsigned);  // 32 KB

    if (ws_size >= th_bytes + flag_bytes) {
        float*    TH  = (float*)d_ws;
        unsigned* flg = (unsigned*)((char*)d_ws + th_bytes);
        hipMemsetAsync(flg, 0, flag_bytes, stream);
        rnn_coop<<<NBLK, NTH, 0, stream>>>(x, h0, Wi2h, Wh2h, out_h, TH, flg);
        h2o_kernel<<<2048, 256, 0, stream>>>(out_h, Wh2o, out_o);
    } else {
        rnn_fallback<<<BB, 512, 0, stream>>>(x, h0, Wi2h, Wh2h, Wh2o, out_o, out_h);
    }
}

// Round 8
// 4994.880 us; speedup vs baseline: 1.2777x; 1.0025x over previous
//
#include <hip/hip_runtime.h>
#include <hip/hip_bf16.h>

#define BB 64
#define TT 1000
#define DD 16
#define HH 1024
#define OO 8

#define NGRP 16         // batch groups
#define GB   4          // batches per group
#define NTH  512

typedef unsigned long long u64;

// ===========================================================================
// x-projection precompute: xp[b][t][h] = sum_d x[b][t][d] * Wi2h[h][d]
// ===========================================================================
__global__ __launch_bounds__(256) void xproj_kernel(
    const float* __restrict__ x,     // [64][1000][16]
    const float* __restrict__ Wi2h,  // [1024][16]
    float* __restrict__ xp)          // [64][1000][1024]
{
    __shared__ float Wl[1024 * 17];  // [h][d] padded 16->17 (bank-safe)
    for (int i = threadIdx.x; i < 1024 * 16; i += 256)
        Wl[(i >> 4) * 17 + (i & 15)] = Wi2h[i];
    __syncthreads();

    const int nrows = BB * TT;
    for (int row = blockIdx.x; row < nrows; row += gridDim.x) {
        float4 xa = *(const float4*)&x[(size_t)row * 16];
        float4 xb = *(const float4*)&x[(size_t)row * 16 + 4];
        float4 xc = *(const float4*)&x[(size_t)row * 16 + 8];
        float4 xd = *(const float4*)&x[(size_t)row * 16 + 12];
#pragma unroll
        for (int c = 0; c < 4; ++c) {
            int hh = threadIdx.x + 256 * c;
            const float* wr = &Wl[hh * 17];
            float s = xa.x * wr[0]  + xa.y * wr[1]  + xa.z * wr[2]  + xa.w * wr[3]
                    + xb.x * wr[4]  + xb.y * wr[5]  + xb.z * wr[6]  + xb.w * wr[7]
                    + xc.x * wr[8]  + xc.y * wr[9]  + xc.z * wr[10] + xc.w * wr[11]
                    + xd.x * wr[12] + xd.y * wr[13] + xd.z * wr[14] + xd.w * wr[15];
            xp[(size_t)row * HH + hh] = s;
        }
    }
}

// ===========================================================================
// Tier-1: SJ=32, 512 blocks (2/CU), W resident in 64 VGPRs/lane.
// Block (bg, js): batches [bg*4,+4), units [js*32,+32).
// Wave w: k-stripe [w*128,+128). Lane = j8 (l&7) x k8 (l>>3):
//   4 j x 16 k x 4 b = 256 FMA/lane/step; W/lane = 64 floats (16 float4).
// th exchange: TH[2][16][4][1024] relaxed-agent stores + 2 flag words per
// (grp, js) (one per finalize wave); consumers poll 8 lanes (4 producers x
// 2 words) then LLC-direct sc0 sc1 stripe loads. Ring WAR safety: each
// block's 8 waves poll producers {4w..4w+3} = ALL 32 blocks of the group,
// so finalize(t+1) happens-after every block's stage-reads(t).
// XPRE=1: x-projection read from precomputed xp (prefetched at loop top).
// XPRE=0: in-kernel x-projection (wi regs + XS staging).
// ===========================================================================
template <int XPRE>
__global__ __launch_bounds__(NTH, 4) void rnn_sj32(
    const float* __restrict__ x,     // [64][1000][16]
    const float* __restrict__ h0,    // [64][1024]
    const float* __restrict__ Wi2h,  // [1024][16]
    const float* Wh2h,               // [1024][1024]
    const float* __restrict__ xp,    // [64][1000][1024] (XPRE=1)
    float* __restrict__ out_h,       // [64][1000][1024]
    float* TH,                       // [2][16][4][1024]
    unsigned* flags)                 // [2][16][32][16]
{
    // THl[w][b][164]: section k8 at offset k8*20 (+kk*4). Compute reads:
    // 8 distinct k8 -> banks {0,20,8,28,16,4,24,12} conflict-free, 8-lane
    // broadcast per addr. b-row stride 164 (656B, 16B-aligned).
    __shared__ __align__(16) float THl[8][4][164];      // 21 KB
    __shared__ float SC[2][4][32][9];                   // 9.2 KB [p][b][j][w]
    __shared__ float XS[2][4][20];                      // XPRE=0 only

    const int tid = threadIdx.x;
    const int w   = tid >> 6;
    const int l   = tid & 63;
    const int bid = blockIdx.x;
    const int bg  = bid & (NGRP - 1);
    const int js  = bid >> 4;         // 0..31

    const int j8 = l & 7;
    const int k8 = l >> 3;            // 0..7 (bits 3-5 -> xor8/16/32 reduce)
    const int jbase = js * 32 + j8 * 4;
    const int kbase = w * 128 + k8 * 16;

    // ---- W patch -> VGPRs: 16 float4 = 64 regs (opaque asm loads) ----
    float4 w4[4][4];
#pragma unroll
    for (int jj = 0; jj < 4; ++jj) {
        const float* a = &Wh2h[(size_t)(jbase + jj) * HH + kbase];
        asm volatile(
            "global_load_dwordx4 %0, %4, off\n\t"
            "global_load_dwordx4 %1, %4, off offset:16\n\t"
            "global_load_dwordx4 %2, %4, off offset:32\n\t"
            "global_load_dwordx4 %3, %4, off offset:48\n\t"
            "s_waitcnt vmcnt(0)"
            : "=&v"(w4[jj][0]), "=&v"(w4[jj][1]), "=&v"(w4[jj][2]), "=&v"(w4[jj][3])
            : "v"(a));
    }

    // ---- finalize role: tid<128 owns (fj = tid&31, fb = (tid>>5)&3) ----
    const int fj = tid & 31, fb = (tid >> 5) & 3;
    float h = 0.f;
    float wi[DD];
    if (tid < 128) {
        h = h0[(size_t)(bg * GB + fb) * HH + js * 32 + fj];
        if (!XPRE) {
#pragma unroll
            for (int d = 0; d < DD; ++d) wi[d] = Wi2h[(js * 32 + fj) * DD + d];
        }
        float th0 = tanhf(h);
        __hip_atomic_store(&TH[((size_t)(0 * NGRP + bg) * GB + fb) * HH + js * 32 + fj],
                           th0, __ATOMIC_RELAXED, __HIP_MEMORY_SCOPE_AGENT);
        asm volatile("s_waitcnt vmcnt(0)" ::: "memory");
        if ((tid & 63) == 0)
            __hip_atomic_store(
                &flags[((size_t)(0 * NGRP + bg) * 32 + js) * 16 + (tid >> 6)],
                1u, __ATOMIC_RELAXED, __HIP_MEMORY_SCOPE_AGENT);
    }

    for (int t = 0; t < TT; ++t) {
        const int p = t & 1;

        // ---- xp prefetch (XPRE): issued before poll, consumed in finalize --
        float xpv = 0.f;
        if (XPRE && tid < 128)
            xpv = xp[((size_t)(bg * GB + fb) * TT + t) * HH + js * 32 + fj];

        // ---- poll: producers pj = 4w + (l>>1), word l&1 (8 lanes) ----
        {
            const unsigned target = (unsigned)(t + 1);
            const unsigned* fa = flags +
                ((size_t)(p * NGRP + bg) * 32 + (4 * w + (l >> 1))) * 16 + (l & 1);
            for (;;) {
                unsigned v = target;
                if (l < 8)
                    v = __hip_atomic_load(fa, __ATOMIC_RELAXED, __HIP_MEMORY_SCOPE_AGENT);
                if (__all((int)(v >= target))) break;
                __builtin_amdgcn_s_sleep(1);
            }
        }

        // ---- stage: lane l -> b = l&3, quads Q0 = l>>2, Q0+16 ----
        {
            const int b = l & 3, Q0 = l >> 2;
            const float* base = TH + ((size_t)(p * NGRP + bg) * GB + b) * HH + w * 128;
            const float* a0 = base + Q0 * 4;
            const float* a1 = base + (Q0 + 16) * 4;
            float4 v0, v1;
            asm volatile("global_load_dwordx4 %0, %2, off sc0 sc1\n\t"
                         "global_load_dwordx4 %1, %3, off sc0 sc1\n\t"
                         "s_waitcnt vmcnt(0)"
                         : "=&v"(v0), "=&v"(v1)
                         : "v"(a0), "v"(a1)
                         : "memory");
            *(float4*)&THl[w][b][(Q0 >> 2) * 20 + (Q0 & 3) * 4] = v0;
            *(float4*)&THl[w][b][((Q0 + 16) >> 2) * 20 + (Q0 & 3) * 4] = v1;
        }
        if (!XPRE && w == 0 && l < 16) {
            int sb2 = l >> 2, dq = (l & 3) * 4;
            float4 v = *(const float4*)&x[((size_t)(bg * GB + sb2) * TT + t) * DD + dq];
            *(float4*)&XS[p][sb2][dq] = v;
        }
        asm volatile("s_waitcnt lgkmcnt(0)" ::: "memory");
        __builtin_amdgcn_sched_barrier(0);

        // ---- compute: acc[jj][m] over lane's 16-k slice x 4 b (256 FMA) ----
        float acc[4][4];
#pragma unroll
        for (int jj = 0; jj < 4; ++jj)
#pragma unroll
            for (int m = 0; m < 4; ++m) acc[jj][m] = 0.f;
#pragma unroll
        for (int kq = 0; kq < 4; ++kq) {
#pragma unroll
            for (int m = 0; m < 4; ++m) {
                float4 tv = *(const float4*)&THl[w][m][k8 * 20 + kq * 4];
#pragma unroll
                for (int jj = 0; jj < 4; ++jj) {
                    acc[jj][m] += w4[jj][kq].x * tv.x;
                    acc[jj][m] += w4[jj][kq].y * tv.y;
                    acc[jj][m] += w4[jj][kq].z * tv.z;
                    acc[jj][m] += w4[jj][kq].w * tv.w;
                }
            }
        }

        // ---- reduce over k8 (xor8/16/32), lanes l<8 publish partials ----
#pragma unroll
        for (int jj = 0; jj < 4; ++jj)
#pragma unroll
            for (int m = 0; m < 4; ++m) {
                float a = acc[jj][m];
                a += __shfl_xor(a, 8, 64);
                a += __shfl_xor(a, 16, 64);
                a += __shfl_xor(a, 32, 64);
                acc[jj][m] = a;
            }
        if (l < 8) {
#pragma unroll
            for (int m = 0; m < 4; ++m)
#pragma unroll
                for (int jj = 0; jj < 4; ++jj)
                    SC[p][m][l * 4 + jj][w] = acc[jj][m];
        }

        __syncthreads();   // the ONE per-step block barrier

        // ---- finalize: h update, TH+flag publish, out_h ----
        if (tid < 128) {
            float z = 0.f;
#pragma unroll
            for (int ww = 0; ww < 8; ++ww) z += SC[p][fb][fj][ww];
            if (!XPRE) {
                xpv = 0.f;
#pragma unroll
                for (int d = 0; d < DD; ++d) xpv += wi[d] * XS[p][fb][d];
            }
            h = 0.9f * h + 0.1f * (z + xpv);
            float th = tanhf(h);
            __hip_atomic_store(
                &TH[((size_t)((p ^ 1) * NGRP + bg) * GB + fb) * HH + js * 32 + fj],
                th, __ATOMIC_RELAXED, __HIP_MEMORY_SCOPE_AGENT);
            asm volatile("s_waitcnt vmcnt(0)" ::: "memory");
            if ((tid & 63) == 0 && t + 1 < TT)
                __hip_atomic_store(
                    &flags[((size_t)((p ^ 1) * NGRP + bg) * 32 + js) * 16 + (tid >> 6)],
                    (unsigned)(t + 2), __ATOMIC_RELAXED, __HIP_MEMORY_SCOPE_AGENT);
            out_h[((size_t)(bg * GB + fb) * TT + t) * HH + js * 32 + fj] = h;
        }
    }
}

// ===========================================================================
// Tier-2: round-7 proven kernel (SJ=64, 256 blocks, 1/CU).
// ===========================================================================
__global__ __launch_bounds__(NTH, 1) void rnn_coop_t2(
    const float* __restrict__ x, const float* __restrict__ h0,
    const float* __restrict__ Wi2h, const float* Wh2h,
    float* __restrict__ out_h, float* TH, unsigned* flags)
{
    __shared__ __align__(16) float THl[8][4][GB][36];
    __shared__ float SC[2][GB][64][9];
    __shared__ float XS[2][GB][20];

    const int tid = threadIdx.x;
    const int w   = tid >> 6;
    const int l   = tid & 63;
    const int bid = blockIdx.x;
    const int bg  = bid & (NGRP - 1);
    const int js  = bid >> 4;         // 0..15

    const int j16 = l & 15;
    const int k4  = l >> 4;
    const int jbase = js * 64 + j16 * 4;
    const int kbase = w * 128 + k4 * 32;

    float4 w4[4][8];
#pragma unroll
    for (int jj = 0; jj < 4; ++jj) {
        const float* a = &Wh2h[(size_t)(jbase + jj) * HH + kbase];
        asm volatile(
            "global_load_dwordx4 %0, %8, off\n\t"
            "global_load_dwordx4 %1, %8, off offset:16\n\t"
            "global_load_dwordx4 %2, %8, off offset:32\n\t"
            "global_load_dwordx4 %3, %8, off offset:48\n\t"
            "global_load_dwordx4 %4, %8, off offset:64\n\t"
            "global_load_dwordx4 %5, %8, off offset:80\n\t"
            "global_load_dwordx4 %6, %8, off offset:96\n\t"
            "global_load_dwordx4 %7, %8, off offset:112\n\t"
            "s_waitcnt vmcnt(0)"
            : "=&v"(w4[jj][0]), "=&v"(w4[jj][1]), "=&v"(w4[jj][2]), "=&v"(w4[jj][3]),
              "=&v"(w4[jj][4]), "=&v"(w4[jj][5]), "=&v"(w4[jj][6]), "=&v"(w4[jj][7])
            : "v"(a));
    }

    const int fb = tid >> 6, fj = tid & 63;
    float h = 0.f;
    float wi[DD];
    if (tid < 256) {
        h = h0[(size_t)(bg * GB + fb) * HH + js * 64 + fj];
#pragma unroll
        for (int d = 0; d < DD; ++d) wi[d] = Wi2h[(js * 64 + fj) * DD + d];
        float th0 = tanhf(h);
        __hip_atomic_store(&TH[((size_t)(0 * NGRP + bg) * GB + fb) * HH + js * 64 + fj],
                           th0, __ATOMIC_RELAXED, __HIP_MEMORY_SCOPE_AGENT);
        asm volatile("s_waitcnt vmcnt(0)" ::: "memory");
        if (l == 0)
            __hip_atomic_store(&flags[((size_t)(0 * NGRP + bg) * 16 + js) * 16 + fb],
                               1u, __ATOMIC_RELAXED, __HIP_MEMORY_SCOPE_AGENT);
    }

    for (int t = 0; t < TT; ++t) {
        const int p = t & 1;
        {
            const unsigned target = (unsigned)(t + 1);
            const unsigned* fa = flags +
                ((size_t)(p * NGRP + bg) * 16 + (2 * w + (l >> 2))) * 16 + (l & 3);
            for (;;) {
                unsigned v = target;
                if (l < 8)
                    v = __hip_atomic_load(fa, __ATOMIC_RELAXED, __HIP_MEMORY_SCOPE_AGENT);
                if (__all((int)(v >= target))) break;
                __builtin_amdgcn_s_sleep(1);
            }
        }
        {
            const int sb = l >> 4, sq = l & 15;
            const float* base = TH + ((size_t)(p * NGRP + bg) * GB + sb) * HH + w * 128;
            const float* a0 = base + sq * 4;
            const float* a1 = base + (sq + 16) * 4;
            float4 v0, v1;
            asm volatile("global_load_dwordx4 %0, %2, off sc0 sc1\n\t"
                         "global_load_dwordx4 %1, %3, off sc0 sc1\n\t"
                         "s_waitcnt vmcnt(0)"
                         : "=&v"(v0), "=&v"(v1)
                         : "v"(a0), "v"(a1)
                         : "memory");
            int k40 = sq >> 3,        kk0 = (sq & 7) ^ k40;
            int k41 = (sq + 16) >> 3, kk1 = (sq & 7) ^ k41;
            *(float4*)&THl[w][k40][sb][kk0 * 4] = v0;
            *(float4*)&THl[w][k41][sb][kk1 * 4] = v1;
        }
        if (w == 0 && l < 16) {
            int sb2 = l >> 2, dq = (l & 3) * 4;
            float4 v = *(const float4*)&x[((size_t)(bg * GB + sb2) * TT + t) * DD + dq];
            *(float4*)&XS[p][sb2][dq] = v;
        }
        asm volatile("s_waitcnt lgkmcnt(0)" ::: "memory");
        __builtin_amdgcn_sched_barrier(0);

        float acc[4][4];
#pragma unroll
        for (int jj = 0; jj < 4; ++jj)
#pragma unroll
            for (int m = 0; m < 4; ++m) acc[jj][m] = 0.f;
#pragma unroll
        for (int kq = 0; kq < 8; ++kq) {
            const int kks = (kq ^ k4) * 4;
#pragma unroll
            for (int m = 0; m < 4; ++m) {
                float4 tv = *(const float4*)&THl[w][k4][m][kks];
#pragma unroll
                for (int jj = 0; jj < 4; ++jj) {
                    acc[jj][m] += w4[jj][kq].x * tv.x;
                    acc[jj][m] += w4[jj][kq].y * tv.y;
                    acc[jj][m] += w4[jj][kq].z * tv.z;
                    acc[jj][m] += w4[jj][kq].w * tv.w;
                }
            }
        }
#pragma unroll
        for (int jj = 0; jj < 4; ++jj)
#pragma unroll
            for (int m = 0; m < 4; ++m) {
                float a = acc[jj][m];
                a += __shfl_xor(a, 16, 64);
                a += __shfl_xor(a, 32, 64);
                acc[jj][m] = a;
            }
        if (k4 == 0) {
#pragma unroll
            for (int m = 0; m < 4; ++m)
#pragma unroll
                for (int jj = 0; jj < 4; ++jj)
                    SC[p][m][j16 * 4 + jj][w] = acc[jj][m];
        }
        __syncthreads();
        if (tid < 256) {
            float z = 0.f;
#pragma unroll
            for (int ww = 0; ww < 8; ++ww) z += SC[p][fb][fj][ww];
            float xpv = 0.f;
#pragma unroll
            for (int d = 0; d < DD; ++d) xpv += wi[d] * XS[p][fb][d];
            h = 0.9f * h + 0.1f * (z + xpv);
            float th = tanhf(h);
            __hip_atomic_store(
                &TH[((size_t)((p ^ 1) * NGRP + bg) * GB + fb) * HH + js * 64 + fj],
                th, __ATOMIC_RELAXED, __HIP_MEMORY_SCOPE_AGENT);
            asm volatile("s_waitcnt vmcnt(0)" ::: "memory");
            if (l == 0 && t + 1 < TT)
                __hip_atomic_store(
                    &flags[((size_t)((p ^ 1) * NGRP + bg) * 16 + js) * 16 + fb],
                    (unsigned)(t + 2), __ATOMIC_RELAXED, __HIP_MEMORY_SCOPE_AGENT);
            out_h[((size_t)(bg * GB + fb) * TT + t) * HH + js * 64 + fj] = h;
        }
    }
}

// ===========================================================================
// h2o: out[b][t][o] = sum_j tanh(h[b][t][j]) * Wh2o[o][j]
// ===========================================================================
__global__ __launch_bounds__(256) void h2o_kernel(
    const float* __restrict__ hs, const float* __restrict__ Wh2o,
    float* __restrict__ out_o)
{
    __shared__ float Wl[OO * HH];
    for (int i = threadIdx.x; i < OO * HH; i += 256) Wl[i] = Wh2o[i];
    __syncthreads();

    const int w = threadIdx.x >> 6, l = threadIdx.x & 63;
    const size_t nrows = (size_t)BB * TT;
    for (size_t row = (size_t)blockIdx.x * 4 + w; row < nrows; row += (size_t)gridDim.x * 4) {
        const float* hr = hs + row * HH;
        float po[OO] = {0.f};
#pragma unroll
        for (int i = 0; i < 16; ++i) {
            int j = l + 64 * i;
            float th = tanhf(hr[j]);
#pragma unroll
            for (int o = 0; o < OO; ++o) po[o] += th * Wl[o * HH + j];
        }
#pragma unroll
        for (int s = 32; s; s >>= 1)
#pragma unroll
            for (int o = 0; o < OO; ++o) po[o] += __shfl_down(po[o], s, 64);
        if (l == 0) {
#pragma unroll
            for (int o = 0; o < OO; ++o) out_o[row * OO + o] = po[o];
        }
    }
}

// ===========================================================================
// Tier-3 fallback (round-1 style, no workspace needed).
// ===========================================================================
__global__ __launch_bounds__(512) void rnn_fallback(
    const float* __restrict__ x, const float* __restrict__ h0,
    const float* __restrict__ Wi2h, const float* __restrict__ W,
    const float* __restrict__ Wh2o, float* __restrict__ out_o,
    float* __restrict__ out_h)
{
    const int b = blockIdx.x, t0 = threadIdx.x, j0 = 2 * t0;
    const int wave = t0 >> 6, lane = t0 & 63;
    __shared__ float th[HH];
    __shared__ float xs[DD];
    __shared__ float ored[8][OO];
    float wi[2][DD];
#pragma unroll
    for (int d = 0; d < DD; ++d) {
        wi[0][d] = Wi2h[j0 * DD + d];
        wi[1][d] = Wi2h[(j0 + 1) * DD + d];
    }
    float wo[2][OO];
#pragma unroll
    for (int o = 0; o < OO; ++o) {
        wo[0][o] = Wh2o[o * HH + j0];
        wo[1][o] = Wh2o[o * HH + j0 + 1];
    }
    float h[2] = { h0[b * HH + j0], h0[b * HH + j0 + 1] };
    th[j0] = tanhf(h[0]); th[j0 + 1] = tanhf(h[1]);
    if (t0 < DD) xs[t0] = x[(size_t)(b * TT) * DD + t0];
    __syncthreads();
    for (int t = 0; t < TT; ++t) {
        float a0 = 0.f, a1 = 0.f;
        const float* r0 = W + (size_t)j0 * HH;
        const float* r1 = W + (size_t)(j0 + 1) * HH;
#pragma unroll 4
        for (int k = 0; k < HH; k += 4) {
            float4 t4 = *(const float4*)&th[k];
            float4 wA = *(const float4*)(r0 + k);
            float4 wB = *(const float4*)(r1 + k);
            a0 += t4.x * wA.x + t4.y * wA.y + t4.z * wA.z + t4.w * wA.w;
            a1 += t4.x * wB.x + t4.y * wB.y + t4.z * wB.z + t4.w * wB.w;
        }
        float xp0 = 0.f, xp1 = 0.f;
#pragma unroll
        for (int d = 0; d < DD; ++d) { xp0 += xs[d] * wi[0][d]; xp1 += xs[d] * wi[1][d]; }
        h[0] = 0.9f * h[0] + 0.1f * (a0 + xp0);
        h[1] = 0.9f * h[1] + 0.1f * (a1 + xp1);
        float th0 = tanhf(h[0]), th1 = tanhf(h[1]);
        *(float2*)&out_h[((size_t)b * TT + t) * HH + j0] = make_float2(h[0], h[1]);
        float po[OO];
#pragma unroll
        for (int o = 0; o < OO; ++o) po[o] = th0 * wo[0][o] + th1 * wo[1][o];
#pragma unroll
        for (int s = 32; s; s >>= 1)
#pragma unroll
            for (int o = 0; o < OO; ++o) po[o] += __shfl_down(po[o], s, 64);
        __syncthreads();
        if (lane == 0)
#pragma unroll
            for (int o = 0; o < OO; ++o) ored[wave][o] = po[o];
        th[j0] = th0; th[j0 + 1] = th1;
        if (t0 < DD && t + 1 < TT) xs[t0] = x[(size_t)(b * TT + t + 1) * DD + t0];
        __syncthreads();
        if (t0 < OO) {
            float s = 0.f;
#pragma unroll
            for (int ww = 0; ww < 8; ++ww) s += ored[ww][t0];
            out_o[((size_t)b * TT + t) * OO + t0] = s;
        }
    }
}

extern "C" void kernel_launch(void* const* d_in, const int* in_sizes, int n_in,
                              void* d_out, int out_size, void* d_ws, size_t ws_size,
                              hipStream_t stream) {
    const float* x    = (const float*)d_in[0];
    const float* h0   = (const float*)d_in[1];
    const float* Wi2h = (const float*)d_in[2];
    const float* Wh2h = (const float*)d_in[3];
    const float* Wh2o = (const float*)d_in[4];

    float* out_o = (float*)d_out;                    // [64][1000][8]
    float* out_h = out_o + (size_t)BB * TT * OO;     // [64][1000][1024]

    const size_t XP_BYTES   = (size_t)BB * TT * HH * sizeof(float);            // 262 MB
    const size_t TH_BYTES   = (size_t)2 * NGRP * GB * HH * sizeof(float);      // 512 KB
    const size_t FLG1_BYTES = (size_t)2 * NGRP * 32 * 16 * sizeof(unsigned);   // 64 KB
    const size_t FLG2_BYTES = (size_t)2 * NGRP * 16 * 16 * sizeof(unsigned);   // 32 KB

    int occ1 = 0, occ0 = 0;
    (void)hipOccupancyMaxActiveBlocksPerMultiprocessor(
        &occ1, reinterpret_cast<const void*>(&rnn_sj32<1>), NTH, 0);
    (void)hipOccupancyMaxActiveBlocksPerMultiprocessor(
        &occ0, reinterpret_cast<const void*>(&rnn_sj32<0>), NTH, 0);

    if (ws_size >= XP_BYTES + TH_BYTES + FLG1_BYTES && occ1 >= 2) {
        float*    xp  = (float*)d_ws;
        float*    TH  = (float*)((char*)d_ws + XP_BYTES);
        unsigned* flg = (unsigned*)((char*)d_ws + XP_BYTES + TH_BYTES);
        hipMemsetAsync(flg, 0, FLG1_BYTES, stream);
        xproj_kernel<<<512, 256, 0, stream>>>(x, Wi2h, xp);
        rnn_sj32<1><<<512, NTH, 0, stream>>>(x, h0, Wi2h, Wh2h, xp, out_h, TH, flg);
        h2o_kernel<<<2048, 256, 0, stream>>>(out_h, Wh2o, out_o);
    } else if (ws_size >= TH_BYTES + FLG1_BYTES && occ0 >= 2) {
        float*    TH  = (float*)d_ws;
        unsigned* flg = (unsigned*)((char*)d_ws + TH_BYTES);
        hipMemsetAsync(flg, 0, FLG1_BYTES, stream);
        rnn_sj32<0><<<512, NTH, 0, stream>>>(x, h0, Wi2h, Wh2h, (const float*)d_ws,
                                             out_h, TH, flg);
        h2o_kernel<<<2048, 256, 0, stream>>>(out_h, Wh2o, out_o);
    } else if (ws_size >= TH_BYTES + FLG2_BYTES) {
        float*    TH  = (float*)d_ws;
        unsigned* flg = (unsigned*)((char*)d_ws + TH_BYTES);
        hipMemsetAsync(flg, 0, FLG2_BYTES, stream);
        rnn_coop_t2<<<256, NTH, 0, stream>>>(x, h0, Wi2h, Wh2h, out_h, TH, flg);
        h2o_kernel<<<2048, 256, 0, stream>>>(out_h, Wh2o, out_o);
    } else {
        rnn_fallback<<<BB, 512, 0, stream>>>(x, h0, Wi2h, Wh2h, Wh2o, out_o, out_h);
    }
}

// Round 9
// 4936.952 us; speedup vs baseline: 1.2927x; 1.0117x over previous
//
#include <hip/hip_runtime.h>
#include <hip/hip_bf16.h>

#define BB 64
#define TT 1000
#define DD 16
#define HH 1024
#define OO 8

#define NGRP 16         // batch groups
#define GB   4          // batches per group
#define NTH  512

typedef unsigned long long u64;

// ---------------------------------------------------------------------------
// Call-free tanh: v_exp_f32 + inline IEEE divide + bit ops. No libcall ->
// no caller-saved VGPR spills around it (the round-5..8 W-spill cause).
// tanh(x) = sign(x) * (1 - 2/(exp2(2*log2e*|x|) + 1)).  Abs err ~6e-8.
// ---------------------------------------------------------------------------
__device__ __forceinline__ float fast_tanh(float x) {
    float ax = __builtin_fabsf(x);
    float e  = __builtin_amdgcn_exp2f(ax * 2.88539008177792681f); // 2*log2(e)
    float r  = 1.0f - 2.0f / (e + 1.0f);
    return __builtin_copysignf(r, x);
}

// ===========================================================================
// x-projection precompute: xp[b][t][h] = sum_d x[b][t][d] * Wi2h[h][d]
// ===========================================================================
__global__ __launch_bounds__(256) void xproj_kernel(
    const float* __restrict__ x,     // [64][1000][16]
    const float* __restrict__ Wi2h,  // [1024][16]
    float* __restrict__ xp)          // [64][1000][1024]
{
    __shared__ float Wl[1024 * 17];  // [h][d] padded 16->17 (bank-safe)
    for (int i = threadIdx.x; i < 1024 * 16; i += 256)
        Wl[(i >> 4) * 17 + (i & 15)] = Wi2h[i];
    __syncthreads();

    const int nrows = BB * TT;
    for (int row = blockIdx.x; row < nrows; row += gridDim.x) {
        float4 xa = *(const float4*)&x[(size_t)row * 16];
        float4 xb = *(const float4*)&x[(size_t)row * 16 + 4];
        float4 xc = *(const float4*)&x[(size_t)row * 16 + 8];
        float4 xd = *(const float4*)&x[(size_t)row * 16 + 12];
#pragma unroll
        for (int c = 0; c < 4; ++c) {
            int hh = threadIdx.x + 256 * c;
            const float* wr = &Wl[hh * 17];
            float s = xa.x * wr[0]  + xa.y * wr[1]  + xa.z * wr[2]  + xa.w * wr[3]
                    + xb.x * wr[4]  + xb.y * wr[5]  + xb.z * wr[6]  + xb.w * wr[7]
                    + xc.x * wr[8]  + xc.y * wr[9]  + xc.z * wr[10] + xc.w * wr[11]
                    + xd.x * wr[12] + xd.y * wr[13] + xd.z * wr[14] + xd.w * wr[15];
            xp[(size_t)row * HH + hh] = s;
        }
    }
}

// ===========================================================================
// Tier-1: SJ=32, 512 blocks (2/CU), W resident in 64 VGPRs/lane.
// Identical to round 8 except fast_tanh (call-free) replaces tanhf.
// ===========================================================================
template <int XPRE>
__global__ __launch_bounds__(NTH, 4) void rnn_sj32(
    const float* __restrict__ x,     // [64][1000][16]
    const float* __restrict__ h0,    // [64][1024]
    const float* __restrict__ Wi2h,  // [1024][16]
    const float* Wh2h,               // [1024][1024]
    const float* __restrict__ xp,    // [64][1000][1024] (XPRE=1)
    float* __restrict__ out_h,       // [64][1000][1024]
    float* TH,                       // [2][16][4][1024]
    unsigned* flags)                 // [2][16][32][16]
{
    __shared__ __align__(16) float THl[8][4][164];      // 21 KB
    __shared__ float SC[2][4][32][9];                   // 9.2 KB [p][b][j][w]
    __shared__ float XS[2][4][20];                      // XPRE=0 only

    const int tid = threadIdx.x;
    const int w   = tid >> 6;
    const int l   = tid & 63;
    const int bid = blockIdx.x;
    const int bg  = bid & (NGRP - 1);
    const int js  = bid >> 4;         // 0..31

    const int j8 = l & 7;
    const int k8 = l >> 3;            // 0..7 (bits 3-5 -> xor8/16/32 reduce)
    const int jbase = js * 32 + j8 * 4;
    const int kbase = w * 128 + k8 * 16;

    // ---- W patch -> VGPRs: 16 float4 = 64 regs (opaque asm loads) ----
    float4 w4[4][4];
#pragma unroll
    for (int jj = 0; jj < 4; ++jj) {
        const float* a = &Wh2h[(size_t)(jbase + jj) * HH + kbase];
        asm volatile(
            "global_load_dwordx4 %0, %4, off\n\t"
            "global_load_dwordx4 %1, %4, off offset:16\n\t"
            "global_load_dwordx4 %2, %4, off offset:32\n\t"
            "global_load_dwordx4 %3, %4, off offset:48\n\t"
            "s_waitcnt vmcnt(0)"
            : "=&v"(w4[jj][0]), "=&v"(w4[jj][1]), "=&v"(w4[jj][2]), "=&v"(w4[jj][3])
            : "v"(a));
    }

    // ---- finalize role: tid<128 owns (fj = tid&31, fb = (tid>>5)&3) ----
    const int fj = tid & 31, fb = (tid >> 5) & 3;
    float h = 0.f;
    float wi[DD];
    if (tid < 128) {
        h = h0[(size_t)(bg * GB + fb) * HH + js * 32 + fj];
        if (!XPRE) {
#pragma unroll
            for (int d = 0; d < DD; ++d) wi[d] = Wi2h[(js * 32 + fj) * DD + d];
        }
        float th0 = fast_tanh(h);
        __hip_atomic_store(&TH[((size_t)(0 * NGRP + bg) * GB + fb) * HH + js * 32 + fj],
                           th0, __ATOMIC_RELAXED, __HIP_MEMORY_SCOPE_AGENT);
        asm volatile("s_waitcnt vmcnt(0)" ::: "memory");
        if ((tid & 63) == 0)
            __hip_atomic_store(
                &flags[((size_t)(0 * NGRP + bg) * 32 + js) * 16 + (tid >> 6)],
                1u, __ATOMIC_RELAXED, __HIP_MEMORY_SCOPE_AGENT);
    }

    for (int t = 0; t < TT; ++t) {
        const int p = t & 1;

        // ---- xp prefetch (XPRE): issued before poll, consumed in finalize --
        float xpv = 0.f;
        if (XPRE && tid < 128)
            xpv = xp[((size_t)(bg * GB + fb) * TT + t) * HH + js * 32 + fj];

        // ---- poll: producers pj = 4w + (l>>1), word l&1 (8 lanes) ----
        {
            const unsigned target = (unsigned)(t + 1);
            const unsigned* fa = flags +
                ((size_t)(p * NGRP + bg) * 32 + (4 * w + (l >> 1))) * 16 + (l & 1);
            for (;;) {
                unsigned v = target;
                if (l < 8)
                    v = __hip_atomic_load(fa, __ATOMIC_RELAXED, __HIP_MEMORY_SCOPE_AGENT);
                if (__all((int)(v >= target))) break;
                __builtin_amdgcn_s_sleep(1);
            }
        }

        // ---- stage: lane l -> b = l&3, quads Q0 = l>>2, Q0+16 ----
        {
            const int b = l & 3, Q0 = l >> 2;
            const float* base = TH + ((size_t)(p * NGRP + bg) * GB + b) * HH + w * 128;
            const float* a0 = base + Q0 * 4;
            const float* a1 = base + (Q0 + 16) * 4;
            float4 v0, v1;
            asm volatile("global_load_dwordx4 %0, %2, off sc0 sc1\n\t"
                         "global_load_dwordx4 %1, %3, off sc0 sc1\n\t"
                         "s_waitcnt vmcnt(0)"
                         : "=&v"(v0), "=&v"(v1)
                         : "v"(a0), "v"(a1)
                         : "memory");
            *(float4*)&THl[w][b][(Q0 >> 2) * 20 + (Q0 & 3) * 4] = v0;
            *(float4*)&THl[w][b][((Q0 + 16) >> 2) * 20 + (Q0 & 3) * 4] = v1;
        }
        if (!XPRE && w == 0 && l < 16) {
            int sb2 = l >> 2, dq = (l & 3) * 4;
            float4 v = *(const float4*)&x[((size_t)(bg * GB + sb2) * TT + t) * DD + dq];
            *(float4*)&XS[p][sb2][dq] = v;
        }
        asm volatile("s_waitcnt lgkmcnt(0)" ::: "memory");
        __builtin_amdgcn_sched_barrier(0);

        // ---- compute: acc[jj][m] over lane's 16-k slice x 4 b (256 FMA) ----
        float acc[4][4];
#pragma unroll
        for (int jj = 0; jj < 4; ++jj)
#pragma unroll
            for (int m = 0; m < 4; ++m) acc[jj][m] = 0.f;
#pragma unroll
        for (int kq = 0; kq < 4; ++kq) {
#pragma unroll
            for (int m = 0; m < 4; ++m) {
                float4 tv = *(const float4*)&THl[w][m][k8 * 20 + kq * 4];
#pragma unroll
                for (int jj = 0; jj < 4; ++jj) {
                    acc[jj][m] += w4[jj][kq].x * tv.x;
                    acc[jj][m] += w4[jj][kq].y * tv.y;
                    acc[jj][m] += w4[jj][kq].z * tv.z;
                    acc[jj][m] += w4[jj][kq].w * tv.w;
                }
            }
        }

        // ---- reduce over k8 (xor8/16/32), lanes l<8 publish partials ----
#pragma unroll
        for (int jj = 0; jj < 4; ++jj)
#pragma unroll
            for (int m = 0; m < 4; ++m) {
                float a = acc[jj][m];
                a += __shfl_xor(a, 8, 64);
                a += __shfl_xor(a, 16, 64);
                a += __shfl_xor(a, 32, 64);
                acc[jj][m] = a;
            }
        if (l < 8) {
#pragma unroll
            for (int m = 0; m < 4; ++m)
#pragma unroll
                for (int jj = 0; jj < 4; ++jj)
                    SC[p][m][l * 4 + jj][w] = acc[jj][m];
        }

        __syncthreads();   // the ONE per-step block barrier

        // ---- finalize: h update, TH+flag publish, out_h ----
        if (tid < 128) {
            float z = 0.f;
#pragma unroll
            for (int ww = 0; ww < 8; ++ww) z += SC[p][fb][fj][ww];
            if (!XPRE) {
                xpv = 0.f;
#pragma unroll
                for (int d = 0; d < DD; ++d) xpv += wi[d] * XS[p][fb][d];
            }
            h = 0.9f * h + 0.1f * (z + xpv);
            float th = fast_tanh(h);
            __hip_atomic_store(
                &TH[((size_t)((p ^ 1) * NGRP + bg) * GB + fb) * HH + js * 32 + fj],
                th, __ATOMIC_RELAXED, __HIP_MEMORY_SCOPE_AGENT);
            asm volatile("s_waitcnt vmcnt(0)" ::: "memory");
            if ((tid & 63) == 0 && t + 1 < TT)
                __hip_atomic_store(
                    &flags[((size_t)((p ^ 1) * NGRP + bg) * 32 + js) * 16 + (tid >> 6)],
                    (unsigned)(t + 2), __ATOMIC_RELAXED, __HIP_MEMORY_SCOPE_AGENT);
            out_h[((size_t)(bg * GB + fb) * TT + t) * HH + js * 32 + fj] = h;
        }
    }
}

// ===========================================================================
// Tier-2: round-7 proven kernel (SJ=64, 256 blocks, 1/CU), fast_tanh.
// ===========================================================================
__global__ __launch_bounds__(NTH, 1) void rnn_coop_t2(
    const float* __restrict__ x, const float* __restrict__ h0,
    const float* __restrict__ Wi2h, const float* Wh2h,
    float* __restrict__ out_h, float* TH, unsigned* flags)
{
    __shared__ __align__(16) float THl[8][4][GB][36];
    __shared__ float SC[2][GB][64][9];
    __shared__ float XS[2][GB][20];

    const int tid = threadIdx.x;
    const int w   = tid >> 6;
    const int l   = tid & 63;
    const int bid = blockIdx.x;
    const int bg  = bid & (NGRP - 1);
    const int js  = bid >> 4;         // 0..15

    const int j16 = l & 15;
    const int k4  = l >> 4;
    const int jbase = js * 64 + j16 * 4;
    const int kbase = w * 128 + k4 * 32;

    float4 w4[4][8];
#pragma unroll
    for (int jj = 0; jj < 4; ++jj) {
        const float* a = &Wh2h[(size_t)(jbase + jj) * HH + kbase];
        asm volatile(
            "global_load_dwordx4 %0, %8, off\n\t"
            "global_load_dwordx4 %1, %8, off offset:16\n\t"
            "global_load_dwordx4 %2, %8, off offset:32\n\t"
            "global_load_dwordx4 %3, %8, off offset:48\n\t"
            "global_load_dwordx4 %4, %8, off offset:64\n\t"
            "global_load_dwordx4 %5, %8, off offset:80\n\t"
            "global_load_dwordx4 %6, %8, off offset:96\n\t"
            "global_load_dwordx4 %7, %8, off offset:112\n\t"
            "s_waitcnt vmcnt(0)"
            : "=&v"(w4[jj][0]), "=&v"(w4[jj][1]), "=&v"(w4[jj][2]), "=&v"(w4[jj][3]),
              "=&v"(w4[jj][4]), "=&v"(w4[jj][5]), "=&v"(w4[jj][6]), "=&v"(w4[jj][7])
            : "v"(a));
    }

    const int fb = tid >> 6, fj = tid & 63;
    float h = 0.f;
    float wi[DD];
    if (tid < 256) {
        h = h0[(size_t)(bg * GB + fb) * HH + js * 64 + fj];
#pragma unroll
        for (int d = 0; d < DD; ++d) wi[d] = Wi2h[(js * 64 + fj) * DD + d];
        float th0 = fast_tanh(h);
        __hip_atomic_store(&TH[((size_t)(0 * NGRP + bg) * GB + fb) * HH + js * 64 + fj],
                           th0, __ATOMIC_RELAXED, __HIP_MEMORY_SCOPE_AGENT);
        asm volatile("s_waitcnt vmcnt(0)" ::: "memory");
        if (l == 0)
            __hip_atomic_store(&flags[((size_t)(0 * NGRP + bg) * 16 + js) * 16 + fb],
                               1u, __ATOMIC_RELAXED, __HIP_MEMORY_SCOPE_AGENT);
    }

    for (int t = 0; t < TT; ++t) {
        const int p = t & 1;
        {
            const unsigned target = (unsigned)(t + 1);
            const unsigned* fa = flags +
                ((size_t)(p * NGRP + bg) * 16 + (2 * w + (l >> 2))) * 16 + (l & 3);
            for (;;) {
                unsigned v = target;
                if (l < 8)
                    v = __hip_atomic_load(fa, __ATOMIC_RELAXED, __HIP_MEMORY_SCOPE_AGENT);
                if (__all((int)(v >= target))) break;
                __builtin_amdgcn_s_sleep(1);
            }
        }
        {
            const int sb = l >> 4, sq = l & 15;
            const float* base = TH + ((size_t)(p * NGRP + bg) * GB + sb) * HH + w * 128;
            const float* a0 = base + sq * 4;
            const float* a1 = base + (sq + 16) * 4;
            float4 v0, v1;
            asm volatile("global_load_dwordx4 %0, %2, off sc0 sc1\n\t"
                         "global_load_dwordx4 %1, %3, off sc0 sc1\n\t"
                         "s_waitcnt vmcnt(0)"
                         : "=&v"(v0), "=&v"(v1)
                         : "v"(a0), "v"(a1)
                         : "memory");
            int k40 = sq >> 3,        kk0 = (sq & 7) ^ k40;
            int k41 = (sq + 16) >> 3, kk1 = (sq & 7) ^ k41;
            *(float4*)&THl[w][k40][sb][kk0 * 4] = v0;
            *(float4*)&THl[w][k41][sb][kk1 * 4] = v1;
        }
        if (w == 0 && l < 16) {
            int sb2 = l >> 2, dq = (l & 3) * 4;
            float4 v = *(const float4*)&x[((size_t)(bg * GB + sb2) * TT + t) * DD + dq];
            *(float4*)&XS[p][sb2][dq] = v;
        }
        asm volatile("s_waitcnt lgkmcnt(0)" ::: "memory");
        __builtin_amdgcn_sched_barrier(0);

        float acc[4][4];
#pragma unroll
        for (int jj = 0; jj < 4; ++jj)
#pragma unroll
            for (int m = 0; m < 4; ++m) acc[jj][m] = 0.f;
#pragma unroll
        for (int kq = 0; kq < 8; ++kq) {
            const int kks = (kq ^ k4) * 4;
#pragma unroll
            for (int m = 0; m < 4; ++m) {
                float4 tv = *(const float4*)&THl[w][k4][m][kks];
#pragma unroll
                for (int jj = 0; jj < 4; ++jj) {
                    acc[jj][m] += w4[jj][kq].x * tv.x;
                    acc[jj][m] += w4[jj][kq].y * tv.y;
                    acc[jj][m] += w4[jj][kq].z * tv.z;
                    acc[jj][m] += w4[jj][kq].w * tv.w;
                }
            }
        }
#pragma unroll
        for (int jj = 0; jj < 4; ++jj)
#pragma unroll
            for (int m = 0; m < 4; ++m) {
                float a = acc[jj][m];
                a += __shfl_xor(a, 16, 64);
                a += __shfl_xor(a, 32, 64);
                acc[jj][m] = a;
            }
        if (k4 == 0) {
#pragma unroll
            for (int m = 0; m < 4; ++m)
#pragma unroll
                for (int jj = 0; jj < 4; ++jj)
                    SC[p][m][j16 * 4 + jj][w] = acc[jj][m];
        }
        __syncthreads();
        if (tid < 256) {
            float z = 0.f;
#pragma unroll
            for (int ww = 0; ww < 8; ++ww) z += SC[p][fb][fj][ww];
            float xpv = 0.f;
#pragma unroll
            for (int d = 0; d < DD; ++d) xpv += wi[d] * XS[p][fb][d];
            h = 0.9f * h + 0.1f * (z + xpv);
            float th = fast_tanh(h);
            __hip_atomic_store(
                &TH[((size_t)((p ^ 1) * NGRP + bg) * GB + fb) * HH + js * 64 + fj],
                th, __ATOMIC_RELAXED, __HIP_MEMORY_SCOPE_AGENT);
            asm volatile("s_waitcnt vmcnt(0)" ::: "memory");
            if (l == 0 && t + 1 < TT)
                __hip_atomic_store(
                    &flags[((size_t)((p ^ 1) * NGRP + bg) * 16 + js) * 16 + fb],
                    (unsigned)(t + 2), __ATOMIC_RELAXED, __HIP_MEMORY_SCOPE_AGENT);
            out_h[((size_t)(bg * GB + fb) * TT + t) * HH + js * 64 + fj] = h;
        }
    }
}

// ===========================================================================
// h2o: out[b][t][o] = sum_j tanh(h[b][t][j]) * Wh2o[o][j]
// ===========================================================================
__global__ __launch_bounds__(256) void h2o_kernel(
    const float* __restrict__ hs, const float* __restrict__ Wh2o,
    float* __restrict__ out_o)
{
    __shared__ float Wl[OO * HH];
    for (int i = threadIdx.x; i < OO * HH; i += 256) Wl[i] = Wh2o[i];
    __syncthreads();

    const int w = threadIdx.x >> 6, l = threadIdx.x & 63;
    const size_t nrows = (size_t)BB * TT;
    for (size_t row = (size_t)blockIdx.x * 4 + w; row < nrows; row += (size_t)gridDim.x * 4) {
        const float* hr = hs + row * HH;
        float po[OO] = {0.f};
#pragma unroll
        for (int i = 0; i < 16; ++i) {
            int j = l + 64 * i;
            float th = tanhf(hr[j]);
#pragma unroll
            for (int o = 0; o < OO; ++o) po[o] += th * Wl[o * HH + j];
        }
#pragma unroll
        for (int s = 32; s; s >>= 1)
#pragma unroll
            for (int o = 0; o < OO; ++o) po[o] += __shfl_down(po[o], s, 64);
        if (l == 0) {
#pragma unroll
            for (int o = 0; o < OO; ++o) out_o[row * OO + o] = po[o];
        }
    }
}

// ===========================================================================
// Tier-3 fallback (round-1 style, no workspace needed).
// ===========================================================================
__global__ __launch_bounds__(512) void rnn_fallback(
    const float* __restrict__ x, const float* __restrict__ h0,
    const float* __restrict__ Wi2h, const float* __restrict__ W,
    const float* __restrict__ Wh2o, float* __restrict__ out_o,
    float* __restrict__ out_h)
{
    const int b = blockIdx.x, t0 = threadIdx.x, j0 = 2 * t0;
    const int wave = t0 >> 6, lane = t0 & 63;
    __shared__ float th[HH];
    __shared__ float xs[DD];
    __shared__ float ored[8][OO];
    float wi[2][DD];
#pragma unroll
    for (int d = 0; d < DD; ++d) {
        wi[0][d] = Wi2h[j0 * DD + d];
        wi[1][d] = Wi2h[(j0 + 1) * DD + d];
    }
    float wo[2][OO];
#pragma unroll
    for (int o = 0; o < OO; ++o) {
        wo[0][o] = Wh2o[o * HH + j0];
        wo[1][o] = Wh2o[o * HH + j0 + 1];
    }
    float h[2] = { h0[b * HH + j0], h0[b * HH + j0 + 1] };
    th[j0] = tanhf(h[0]); th[j0 + 1] = tanhf(h[1]);
    if (t0 < DD) xs[t0] = x[(size_t)(b * TT) * DD + t0];
    __syncthreads();
    for (int t = 0; t < TT; ++t) {
        float a0 = 0.f, a1 = 0.f;
        const float* r0 = W + (size_t)j0 * HH;
        const float* r1 = W + (size_t)(j0 + 1) * HH;
#pragma unroll 4
        for (int k = 0; k < HH; k += 4) {
            float4 t4 = *(const float4*)&th[k];
            float4 wA = *(const float4*)(r0 + k);
            float4 wB = *(const float4*)(r1 + k);
            a0 += t4.x * wA.x + t4.y * wA.y + t4.z * wA.z + t4.w * wA.w;
            a1 += t4.x * wB.x + t4.y * wB.y + t4.z * wB.z + t4.w * wB.w;
        }
        float xp0 = 0.f, xp1 = 0.f;
#pragma unroll
        for (int d = 0; d < DD; ++d) { xp0 += xs[d] * wi[0][d]; xp1 += xs[d] * wi[1][d]; }
        h[0] = 0.9f * h[0] + 0.1f * (a0 + xp0);
        h[1] = 0.9f * h[1] + 0.1f * (a1 + xp1);
        float th0 = tanhf(h[0]), th1 = tanhf(h[1]);
        *(float2*)&out_h[((size_t)b * TT + t) * HH + j0] = make_float2(h[0], h[1]);
        float po[OO];
#pragma unroll
        for (int o = 0; o < OO; ++o) po[o] = th0 * wo[0][o] + th1 * wo[1][o];
#pragma unroll
        for (int s = 32; s; s >>= 1)
#pragma unroll
            for (int o = 0; o < OO; ++o) po[o] += __shfl_down(po[o], s, 64);
        __syncthreads();
        if (lane == 0)
#pragma unroll
            for (int o = 0; o < OO; ++o) ored[wave][o] = po[o];
        th[j0] = th0; th[j0 + 1] = th1;
        if (t0 < DD && t + 1 < TT) xs[t0] = x[(size_t)(b * TT + t + 1) * DD + t0];
        __syncthreads();
        if (t0 < OO) {
            float s = 0.f;
#pragma unroll
            for (int ww = 0; ww < 8; ++ww) s += ored[ww][t0];
            out_o[((size_t)b * TT + t) * OO + t0] = s;
        }
    }
}

extern "C" void kernel_launch(void* const* d_in, const int* in_sizes, int n_in,
                              void* d_out, int out_size, void* d_ws, size_t ws_size,
                              hipStream_t stream) {
    const float* x    = (const float*)d_in[0];
    const float* h0   = (const float*)d_in[1];
    const float* Wi2h = (const float*)d_in[2];
    const float* Wh2h = (const float*)d_in[3];
    const float* Wh2o = (const float*)d_in[4];

    float* out_o = (float*)d_out;                    // [64][1000][8]
    float* out_h = out_o + (size_t)BB * TT * OO;     // [64][1000][1024]

    const size_t XP_BYTES   = (size_t)BB * TT * HH * sizeof(float);            // 262 MB
    const size_t TH_BYTES   = (size_t)2 * NGRP * GB * HH * sizeof(float);      // 512 KB
    const size_t FLG1_BYTES = (size_t)2 * NGRP * 32 * 16 * sizeof(unsigned);   // 64 KB
    const size_t FLG2_BYTES = (size_t)2 * NGRP * 16 * 16 * sizeof(unsigned);   // 32 KB

    int occ1 = 0, occ0 = 0;
    (void)hipOccupancyMaxActiveBlocksPerMultiprocessor(
        &occ1, reinterpret_cast<const void*>(&rnn_sj32<1>), NTH, 0);
    (void)hipOccupancyMaxActiveBlocksPerMultiprocessor(
        &occ0, reinterpret_cast<const void*>(&rnn_sj32<0>), NTH, 0);

    if (ws_size >= XP_BYTES + TH_BYTES + FLG1_BYTES && occ1 >= 2) {
        float*    xp  = (float*)d_ws;
        float*    TH  = (float*)((char*)d_ws + XP_BYTES);
        unsigned* flg = (unsigned*)((char*)d_ws + XP_BYTES + TH_BYTES);
        hipMemsetAsync(flg, 0, FLG1_BYTES, stream);
        xproj_kernel<<<512, 256, 0, stream>>>(x, Wi2h, xp);
        rnn_sj32<1><<<512, NTH, 0, stream>>>(x, h0, Wi2h, Wh2h, xp, out_h, TH, flg);
        h2o_kernel<<<2048, 256, 0, stream>>>(out_h, Wh2o, out_o);
    } else if (ws_size >= TH_BYTES + FLG1_BYTES && occ0 >= 2) {
        float*    TH  = (float*)d_ws;
        unsigned* flg = (unsigned*)((char*)d_ws + TH_BYTES);
        hipMemsetAsync(flg, 0, FLG1_BYTES, stream);
        rnn_sj32<0><<<512, NTH, 0, stream>>>(x, h0, Wi2h, Wh2h, (const float*)d_ws,
                                             out_h, TH, flg);
        h2o_kernel<<<2048, 256, 0, stream>>>(out_h, Wh2o, out_o);
    } else if (ws_size >= TH_BYTES + FLG2_BYTES) {
        float*    TH  = (float*)d_ws;
        unsigned* flg = (unsigned*)((char*)d_ws + TH_BYTES);
        hipMemsetAsync(flg, 0, FLG2_BYTES, stream);
        rnn_coop_t2<<<256, NTH, 0, stream>>>(x, h0, Wi2h, Wh2h, out_h, TH, flg);
        h2o_kernel<<<2048, 256, 0, stream>>>(out_h, Wh2o, out_o);
    } else {
        rnn_fallback<<<BB, 512, 0, stream>>>(x, h0, Wi2h, Wh2h, Wh2o, out_o, out_h);
    }
}

// Round 10
// 4925.569 us; speedup vs baseline: 1.2957x; 1.0023x over previous
//
#include <hip/hip_runtime.h>
#include <hip/hip_bf16.h>

#define BB 64
#define TT 1000
#define DD 16
#define HH 1024
#define OO 8

#define NGRP 16         // batch groups
#define GB   4          // batches per group
#define NTH  512

typedef unsigned long long u64;

// ---------------------------------------------------------------------------
// Call-free tanh (no libcall): sign(x) * (1 - 2/(exp2(2*log2e*|x|)+1)).
// ---------------------------------------------------------------------------
__device__ __forceinline__ float fast_tanh(float x) {
    float ax = __builtin_fabsf(x);
    float e  = __builtin_amdgcn_exp2f(ax * 2.88539008177792681f); // 2*log2(e)
    float r  = 1.0f - 2.0f / (e + 1.0f);
    return __builtin_copysignf(r, x);
}

// ===========================================================================
// x-projection precompute: xp[b][t][h] = sum_d x[b][t][d] * Wi2h[h][d]
// ===========================================================================
__global__ __launch_bounds__(256) void xproj_kernel(
    const float* __restrict__ x,     // [64][1000][16]
    const float* __restrict__ Wi2h,  // [1024][16]
    float* __restrict__ xp)          // [64][1000][1024]
{
    __shared__ float Wl[1024 * 17];
    for (int i = threadIdx.x; i < 1024 * 16; i += 256)
        Wl[(i >> 4) * 17 + (i & 15)] = Wi2h[i];
    __syncthreads();

    const int nrows = BB * TT;
    for (int row = blockIdx.x; row < nrows; row += gridDim.x) {
        float4 xa = *(const float4*)&x[(size_t)row * 16];
        float4 xb = *(const float4*)&x[(size_t)row * 16 + 4];
        float4 xc = *(const float4*)&x[(size_t)row * 16 + 8];
        float4 xd = *(const float4*)&x[(size_t)row * 16 + 12];
#pragma unroll
        for (int c = 0; c < 4; ++c) {
            int hh = threadIdx.x + 256 * c;
            const float* wr = &Wl[hh * 17];
            float s = xa.x * wr[0]  + xa.y * wr[1]  + xa.z * wr[2]  + xa.w * wr[3]
                    + xb.x * wr[4]  + xb.y * wr[5]  + xb.z * wr[6]  + xb.w * wr[7]
                    + xc.x * wr[8]  + xc.y * wr[9]  + xc.z * wr[10] + xc.w * wr[11]
                    + xd.x * wr[12] + xd.y * wr[13] + xd.z * wr[14] + xd.w * wr[15];
            xp[(size_t)row * HH + hh] = s;
        }
    }
}

// ===========================================================================
// Tier-1: SJ=32, 512 blocks (2/CU). Round-9 structure + XCD-local fast path:
// prologue reads HW_REG_XCC_ID per block, publishes it (sc1), and each block
// checks whether ALL 32 producers of its group share its XCD. If yes (group-
// uniform decision): th/flag exchange uses plain write-through stores + sc0
// (L1-bypass) loads -> per-XCD L2 round trips instead of LLC. If no: the
// proven sc1 LLC protocol. Ring/WAR safety identical to round 9 (flags gate
// every TH read; finalize(t+1) happens-after all blocks' stage-reads(t)).
// ===========================================================================
template <int XPRE>
__global__ __launch_bounds__(NTH, 4) void rnn_sj32(
    const float* __restrict__ x,     // [64][1000][16]
    const float* __restrict__ h0,    // [64][1024]
    const float* __restrict__ Wi2h,  // [1024][16]
    const float* Wh2h,               // [1024][1024]
    const float* __restrict__ xp,    // [64][1000][1024] (XPRE=1)
    float* __restrict__ out_h,       // [64][1000][1024]
    float* TH,                       // [2][16][4][1024]
    unsigned* flags,                 // [2][16][32][16] (memset 0 per launch)
    unsigned* ids)                   // [16][32]
{
    __shared__ __align__(16) float THl[8][4][164];      // 21 KB
    __shared__ float SC[2][4][32][9];                   // 9.2 KB [p][b][j][w]
    __shared__ float XS[2][4][20];                      // XPRE=0 only

    const int tid = threadIdx.x;
    const int w   = tid >> 6;
    const int l   = tid & 63;
    const int bid = blockIdx.x;
    const int bg  = bid & (NGRP - 1);
    const int js  = bid >> 4;         // 0..31

    const int j8 = l & 7;
    const int k8 = l >> 3;
    const int jbase = js * 32 + j8 * 4;
    const int kbase = w * 128 + k8 * 16;

    unsigned myid;
    asm volatile("s_getreg_b32 %0, hwreg(HW_REG_XCC_ID)" : "=s"(myid));

    // ---- W patch -> VGPR/AGPR file: 16 float4 (opaque asm loads) ----
    float4 w4[4][4];
#pragma unroll
    for (int jj = 0; jj < 4; ++jj) {
        const float* a = &Wh2h[(size_t)(jbase + jj) * HH + kbase];
        asm volatile(
            "global_load_dwordx4 %0, %4, off\n\t"
            "global_load_dwordx4 %1, %4, off offset:16\n\t"
            "global_load_dwordx4 %2, %4, off offset:32\n\t"
            "global_load_dwordx4 %3, %4, off offset:48\n\t"
            "s_waitcnt vmcnt(0)"
            : "=&v"(w4[jj][0]), "=&v"(w4[jj][1]), "=&v"(w4[jj][2]), "=&v"(w4[jj][3])
            : "v"(a));
    }

    // ---- init: publish XCD id, th(0), then flags=1 (all sc1/LLC) ----
    const int fj = tid & 31, fb = (tid >> 5) & 3;
    float h = 0.f;
    float wi[DD];
    if (tid == 0)
        __hip_atomic_store(&ids[bg * 32 + js], myid,
                           __ATOMIC_RELAXED, __HIP_MEMORY_SCOPE_AGENT);
    if (tid < 128) {
        h = h0[(size_t)(bg * GB + fb) * HH + js * 32 + fj];
        if (!XPRE) {
#pragma unroll
            for (int d = 0; d < DD; ++d) wi[d] = Wi2h[(js * 32 + fj) * DD + d];
        }
        float th0 = fast_tanh(h);
        __hip_atomic_store(&TH[((size_t)(0 * NGRP + bg) * GB + fb) * HH + js * 32 + fj],
                           th0, __ATOMIC_RELAXED, __HIP_MEMORY_SCOPE_AGENT);
        asm volatile("s_waitcnt vmcnt(0)" ::: "memory");
        if ((tid & 63) == 0)
            __hip_atomic_store(
                &flags[((size_t)(0 * NGRP + bg) * 32 + js) * 16 + (tid >> 6)],
                1u, __ATOMIC_RELAXED, __HIP_MEMORY_SCOPE_AGENT);
    }

    // ---- prologue: wait all 32 producers present, then XCD-uniformity ----
    bool fastp;
    {
        const unsigned* fa = flags +
            ((size_t)(0 * NGRP + bg) * 32 + (l >> 1)) * 16 + (l & 1);
        for (;;) {
            unsigned v;
            asm volatile("global_load_dword %0, %1, off sc0 sc1\n\ts_waitcnt vmcnt(0)"
                         : "=v"(v) : "v"(fa) : "memory");
            if (__all((int)(v >= 1u))) break;
            __builtin_amdgcn_s_sleep(1);
        }
        unsigned idv = myid;
        if (l < 32) {
            const unsigned* ia = ids + bg * 32 + l;
            asm volatile("global_load_dword %0, %1, off sc0 sc1\n\ts_waitcnt vmcnt(0)"
                         : "=v"(idv) : "v"(ia) : "memory");
        }
        fastp = __all((int)(idv == myid));
    }

    for (int t = 0; t < TT; ++t) {
        const int p = t & 1;

        // ---- xp prefetch (XPRE) ----
        float xpv = 0.f;
        if (XPRE && tid < 128)
            xpv = xp[((size_t)(bg * GB + fb) * TT + t) * HH + js * 32 + fj];

        // ---- poll: producers pj = 4w + (l>>1), word l&1 (8 lanes) ----
        {
            const unsigned target = (unsigned)(t + 1);
            const unsigned* fa = flags +
                ((size_t)(p * NGRP + bg) * 32 + (4 * w + (l >> 1))) * 16 + (l & 1);
            if (fastp) {
                for (;;) {
                    unsigned v = target;
                    if (l < 8)
                        asm volatile("global_load_dword %0, %1, off sc0\n\ts_waitcnt vmcnt(0)"
                                     : "=v"(v) : "v"(fa) : "memory");
                    if (__all((int)(v >= target))) break;
                    __builtin_amdgcn_s_sleep(1);
                }
            } else {
                for (;;) {
                    unsigned v = target;
                    if (l < 8)
                        v = __hip_atomic_load(fa, __ATOMIC_RELAXED,
                                              __HIP_MEMORY_SCOPE_AGENT);
                    if (__all((int)(v >= target))) break;
                    __builtin_amdgcn_s_sleep(1);
                }
            }
        }

        // ---- stage: lane l -> b = l&3, quads Q0 = l>>2, Q0+16 ----
        {
            const int b = l & 3, Q0 = l >> 2;
            const float* base = TH + ((size_t)(p * NGRP + bg) * GB + b) * HH + w * 128;
            const float* a0 = base + Q0 * 4;
            const float* a1 = base + (Q0 + 16) * 4;
            float4 v0, v1;
            if (fastp)
                asm volatile("global_load_dwordx4 %0, %2, off sc0\n\t"
                             "global_load_dwordx4 %1, %3, off sc0\n\t"
                             "s_waitcnt vmcnt(0)"
                             : "=&v"(v0), "=&v"(v1)
                             : "v"(a0), "v"(a1) : "memory");
            else
                asm volatile("global_load_dwordx4 %0, %2, off sc0 sc1\n\t"
                             "global_load_dwordx4 %1, %3, off sc0 sc1\n\t"
                             "s_waitcnt vmcnt(0)"
                             : "=&v"(v0), "=&v"(v1)
                             : "v"(a0), "v"(a1) : "memory");
            *(float4*)&THl[w][b][(Q0 >> 2) * 20 + (Q0 & 3) * 4] = v0;
            *(float4*)&THl[w][b][((Q0 + 16) >> 2) * 20 + (Q0 & 3) * 4] = v1;
        }
        if (!XPRE && w == 0 && l < 16) {
            int sb2 = l >> 2, dq = (l & 3) * 4;
            float4 v = *(const float4*)&x[((size_t)(bg * GB + sb2) * TT + t) * DD + dq];
            *(float4*)&XS[p][sb2][dq] = v;
        }
        asm volatile("s_waitcnt lgkmcnt(0)" ::: "memory");
        __builtin_amdgcn_sched_barrier(0);

        // ---- compute: acc[jj][m] over lane's 16-k slice x 4 b (256 FMA) ----
        float acc[4][4];
#pragma unroll
        for (int jj = 0; jj < 4; ++jj)
#pragma unroll
            for (int m = 0; m < 4; ++m) acc[jj][m] = 0.f;
#pragma unroll
        for (int kq = 0; kq < 4; ++kq) {
#pragma unroll
            for (int m = 0; m < 4; ++m) {
                float4 tv = *(const float4*)&THl[w][m][k8 * 20 + kq * 4];
#pragma unroll
                for (int jj = 0; jj < 4; ++jj) {
                    acc[jj][m] += w4[jj][kq].x * tv.x;
                    acc[jj][m] += w4[jj][kq].y * tv.y;
                    acc[jj][m] += w4[jj][kq].z * tv.z;
                    acc[jj][m] += w4[jj][kq].w * tv.w;
                }
            }
        }

        // ---- reduce over k8 (xor8/16/32), lanes l<8 publish partials ----
#pragma unroll
        for (int jj = 0; jj < 4; ++jj)
#pragma unroll
            for (int m = 0; m < 4; ++m) {
                float a = acc[jj][m];
                a += __shfl_xor(a, 8, 64);
                a += __shfl_xor(a, 16, 64);
                a += __shfl_xor(a, 32, 64);
                acc[jj][m] = a;
            }
        if (l < 8) {
#pragma unroll
            for (int m = 0; m < 4; ++m)
#pragma unroll
                for (int jj = 0; jj < 4; ++jj)
                    SC[p][m][l * 4 + jj][w] = acc[jj][m];
        }

        __syncthreads();   // the ONE per-step block barrier

        // ---- finalize: h update, TH+flag publish, out_h ----
        if (tid < 128) {
            float z = 0.f;
#pragma unroll
            for (int ww = 0; ww < 8; ++ww) z += SC[p][fb][fj][ww];
            if (!XPRE) {
                xpv = 0.f;
#pragma unroll
                for (int d = 0; d < DD; ++d) xpv += wi[d] * XS[p][fb][d];
            }
            h = 0.9f * h + 0.1f * (z + xpv);
            float th = fast_tanh(h);
            float* ta = &TH[((size_t)((p ^ 1) * NGRP + bg) * GB + fb) * HH + js * 32 + fj];
            if (fastp)
                asm volatile("global_store_dword %0, %1, off"
                             :: "v"(ta), "v"(th) : "memory");
            else
                __hip_atomic_store(ta, th, __ATOMIC_RELAXED, __HIP_MEMORY_SCOPE_AGENT);
            asm volatile("s_waitcnt vmcnt(0)" ::: "memory");
            if ((tid & 63) == 0 && t + 1 < TT) {
                unsigned* fla =
                    &flags[((size_t)((p ^ 1) * NGRP + bg) * 32 + js) * 16 + (tid >> 6)];
                unsigned fv = (unsigned)(t + 2);
                if (fastp)
                    asm volatile("global_store_dword %0, %1, off"
                                 :: "v"(fla), "v"(fv) : "memory");
                else
                    __hip_atomic_store(fla, fv, __ATOMIC_RELAXED,
                                       __HIP_MEMORY_SCOPE_AGENT);
            }
            out_h[((size_t)(bg * GB + fb) * TT + t) * HH + js * 32 + fj] = h;
        }
    }
}

// ===========================================================================
// Tier-2: round-7 proven kernel (SJ=64, 256 blocks, 1/CU), fast_tanh.
// ===========================================================================
__global__ __launch_bounds__(NTH, 1) void rnn_coop_t2(
    const float* __restrict__ x, const float* __restrict__ h0,
    const float* __restrict__ Wi2h, const float* Wh2h,
    float* __restrict__ out_h, float* TH, unsigned* flags)
{
    __shared__ __align__(16) float THl[8][4][GB][36];
    __shared__ float SC[2][GB][64][9];
    __shared__ float XS[2][GB][20];

    const int tid = threadIdx.x;
    const int w   = tid >> 6;
    const int l   = tid & 63;
    const int bid = blockIdx.x;
    const int bg  = bid & (NGRP - 1);
    const int js  = bid >> 4;

    const int j16 = l & 15;
    const int k4  = l >> 4;
    const int jbase = js * 64 + j16 * 4;
    const int kbase = w * 128 + k4 * 32;

    float4 w4[4][8];
#pragma unroll
    for (int jj = 0; jj < 4; ++jj) {
        const float* a = &Wh2h[(size_t)(jbase + jj) * HH + kbase];
        asm volatile(
            "global_load_dwordx4 %0, %8, off\n\t"
            "global_load_dwordx4 %1, %8, off offset:16\n\t"
            "global_load_dwordx4 %2, %8, off offset:32\n\t"
            "global_load_dwordx4 %3, %8, off offset:48\n\t"
            "global_load_dwordx4 %4, %8, off offset:64\n\t"
            "global_load_dwordx4 %5, %8, off offset:80\n\t"
            "global_load_dwordx4 %6, %8, off offset:96\n\t"
            "global_load_dwordx4 %7, %8, off offset:112\n\t"
            "s_waitcnt vmcnt(0)"
            : "=&v"(w4[jj][0]), "=&v"(w4[jj][1]), "=&v"(w4[jj][2]), "=&v"(w4[jj][3]),
              "=&v"(w4[jj][4]), "=&v"(w4[jj][5]), "=&v"(w4[jj][6]), "=&v"(w4[jj][7])
            : "v"(a));
    }

    const int fb = tid >> 6, fj = tid & 63;
    float h = 0.f;
    float wi[DD];
    if (tid < 256) {
        h = h0[(size_t)(bg * GB + fb) * HH + js * 64 + fj];
#pragma unroll
        for (int d = 0; d < DD; ++d) wi[d] = Wi2h[(js * 64 + fj) * DD + d];
        float th0 = fast_tanh(h);
        __hip_atomic_store(&TH[((size_t)(0 * NGRP + bg) * GB + fb) * HH + js * 64 + fj],
                           th0, __ATOMIC_RELAXED, __HIP_MEMORY_SCOPE_AGENT);
        asm volatile("s_waitcnt vmcnt(0)" ::: "memory");
        if (l == 0)
            __hip_atomic_store(&flags[((size_t)(0 * NGRP + bg) * 16 + js) * 16 + fb],
                               1u, __ATOMIC_RELAXED, __HIP_MEMORY_SCOPE_AGENT);
    }

    for (int t = 0; t < TT; ++t) {
        const int p = t & 1;
        {
            const unsigned target = (unsigned)(t + 1);
            const unsigned* fa = flags +
                ((size_t)(p * NGRP + bg) * 16 + (2 * w + (l >> 2))) * 16 + (l & 3);
            for (;;) {
                unsigned v = target;
                if (l < 8)
                    v = __hip_atomic_load(fa, __ATOMIC_RELAXED, __HIP_MEMORY_SCOPE_AGENT);
                if (__all((int)(v >= target))) break;
                __builtin_amdgcn_s_sleep(1);
            }
        }
        {
            const int sb = l >> 4, sq = l & 15;
            const float* base = TH + ((size_t)(p * NGRP + bg) * GB + sb) * HH + w * 128;
            const float* a0 = base + sq * 4;
            const float* a1 = base + (sq + 16) * 4;
            float4 v0, v1;
            asm volatile("global_load_dwordx4 %0, %2, off sc0 sc1\n\t"
                         "global_load_dwordx4 %1, %3, off sc0 sc1\n\t"
                         "s_waitcnt vmcnt(0)"
                         : "=&v"(v0), "=&v"(v1)
                         : "v"(a0), "v"(a1)
                         : "memory");
            int k40 = sq >> 3,        kk0 = (sq & 7) ^ k40;
            int k41 = (sq + 16) >> 3, kk1 = (sq & 7) ^ k41;
            *(float4*)&THl[w][k40][sb][kk0 * 4] = v0;
            *(float4*)&THl[w][k41][sb][kk1 * 4] = v1;
        }
        if (w == 0 && l < 16) {
            int sb2 = l >> 2, dq = (l & 3) * 4;
            float4 v = *(const float4*)&x[((size_t)(bg * GB + sb2) * TT + t) * DD + dq];
            *(float4*)&XS[p][sb2][dq] = v;
        }
        asm volatile("s_waitcnt lgkmcnt(0)" ::: "memory");
        __builtin_amdgcn_sched_barrier(0);

        float acc[4][4];
#pragma unroll
        for (int jj = 0; jj < 4; ++jj)
#pragma unroll
            for (int m = 0; m < 4; ++m) acc[jj][m] = 0.f;
#pragma unroll
        for (int kq = 0; kq < 8; ++kq) {
            const int kks = (kq ^ k4) * 4;
#pragma unroll
            for (int m = 0; m < 4; ++m) {
                float4 tv = *(const float4*)&THl[w][k4][m][kks];
#pragma unroll
                for (int jj = 0; jj < 4; ++jj) {
                    acc[jj][m] += w4[jj][kq].x * tv.x;
                    acc[jj][m] += w4[jj][kq].y * tv.y;
                    acc[jj][m] += w4[jj][kq].z * tv.z;
                    acc[jj][m] += w4[jj][kq].w * tv.w;
                }
            }
        }
#pragma unroll
        for (int jj = 0; jj < 4; ++jj)
#pragma unroll
            for (int m = 0; m < 4; ++m) {
                float a = acc[jj][m];
                a += __shfl_xor(a, 16, 64);
                a += __shfl_xor(a, 32, 64);
                acc[jj][m] = a;
            }
        if (k4 == 0) {
#pragma unroll
            for (int m = 0; m < 4; ++m)
#pragma unroll
                for (int jj = 0; jj < 4; ++jj)
                    SC[p][m][j16 * 4 + jj][w] = acc[jj][m];
        }
        __syncthreads();
        if (tid < 256) {
            float z = 0.f;
#pragma unroll
            for (int ww = 0; ww < 8; ++ww) z += SC[p][fb][fj][ww];
            float xpv = 0.f;
#pragma unroll
            for (int d = 0; d < DD; ++d) xpv += wi[d] * XS[p][fb][d];
            h = 0.9f * h + 0.1f * (z + xpv);
            float th = fast_tanh(h);
            __hip_atomic_store(
                &TH[((size_t)((p ^ 1) * NGRP + bg) * GB + fb) * HH + js * 64 + fj],
                th, __ATOMIC_RELAXED, __HIP_MEMORY_SCOPE_AGENT);
            asm volatile("s_waitcnt vmcnt(0)" ::: "memory");
            if (l == 0 && t + 1 < TT)
                __hip_atomic_store(
                    &flags[((size_t)((p ^ 1) * NGRP + bg) * 16 + js) * 16 + fb],
                    (unsigned)(t + 2), __ATOMIC_RELAXED, __HIP_MEMORY_SCOPE_AGENT);
            out_h[((size_t)(bg * GB + fb) * TT + t) * HH + js * 64 + fj] = h;
        }
    }
}

// ===========================================================================
// h2o: out[b][t][o] = sum_j tanh(h[b][t][j]) * Wh2o[o][j]
// ===========================================================================
__global__ __launch_bounds__(256) void h2o_kernel(
    const float* __restrict__ hs, const float* __restrict__ Wh2o,
    float* __restrict__ out_o)
{
    __shared__ float Wl[OO * HH];
    for (int i = threadIdx.x; i < OO * HH; i += 256) Wl[i] = Wh2o[i];
    __syncthreads();

    const int w = threadIdx.x >> 6, l = threadIdx.x & 63;
    const size_t nrows = (size_t)BB * TT;
    for (size_t row = (size_t)blockIdx.x * 4 + w; row < nrows; row += (size_t)gridDim.x * 4) {
        const float* hr = hs + row * HH;
        float po[OO] = {0.f};
#pragma unroll
        for (int i = 0; i < 16; ++i) {
            int j = l + 64 * i;
            float th = tanhf(hr[j]);
#pragma unroll
            for (int o = 0; o < OO; ++o) po[o] += th * Wl[o * HH + j];
        }
#pragma unroll
        for (int s = 32; s; s >>= 1)
#pragma unroll
            for (int o = 0; o < OO; ++o) po[o] += __shfl_down(po[o], s, 64);
        if (l == 0) {
#pragma unroll
            for (int o = 0; o < OO; ++o) out_o[row * OO + o] = po[o];
        }
    }
}

// ===========================================================================
// Tier-3 fallback (round-1 style, no workspace needed).
// ===========================================================================
__global__ __launch_bounds__(512) void rnn_fallback(
    const float* __restrict__ x, const float* __restrict__ h0,
    const float* __restrict__ Wi2h, const float* __restrict__ W,
    const float* __restrict__ Wh2o, float* __restrict__ out_o,
    float* __restrict__ out_h)
{
    const int b = blockIdx.x, t0 = threadIdx.x, j0 = 2 * t0;
    const int wave = t0 >> 6, lane = t0 & 63;
    __shared__ float th[HH];
    __shared__ float xs[DD];
    __shared__ float ored[8][OO];
    float wi[2][DD];
#pragma unroll
    for (int d = 0; d < DD; ++d) {
        wi[0][d] = Wi2h[j0 * DD + d];
        wi[1][d] = Wi2h[(j0 + 1) * DD + d];
    }
    float wo[2][OO];
#pragma unroll
    for (int o = 0; o < OO; ++o) {
        wo[0][o] = Wh2o[o * HH + j0];
        wo[1][o] = Wh2o[o * HH + j0 + 1];
    }
    float h[2] = { h0[b * HH + j0], h0[b * HH + j0 + 1] };
    th[j0] = tanhf(h[0]); th[j0 + 1] = tanhf(h[1]);
    if (t0 < DD) xs[t0] = x[(size_t)(b * TT) * DD + t0];
    __syncthreads();
    for (int t = 0; t < TT; ++t) {
        float a0 = 0.f, a1 = 0.f;
        const float* r0 = W + (size_t)j0 * HH;
        const float* r1 = W + (size_t)(j0 + 1) * HH;
#pragma unroll 4
        for (int k = 0; k < HH; k += 4) {
            float4 t4 = *(const float4*)&th[k];
            float4 wA = *(const float4*)(r0 + k);
            float4 wB = *(const float4*)(r1 + k);
            a0 += t4.x * wA.x + t4.y * wA.y + t4.z * wA.z + t4.w * wA.w;
            a1 += t4.x * wB.x + t4.y * wB.y + t4.z * wB.z + t4.w * wB.w;
        }
        float xp0 = 0.f, xp1 = 0.f;
#pragma unroll
        for (int d = 0; d < DD; ++d) { xp0 += xs[d] * wi[0][d]; xp1 += xs[d] * wi[1][d]; }
        h[0] = 0.9f * h[0] + 0.1f * (a0 + xp0);
        h[1] = 0.9f * h[1] + 0.1f * (a1 + xp1);
        float th0 = tanhf(h[0]), th1 = tanhf(h[1]);
        *(float2*)&out_h[((size_t)b * TT + t) * HH + j0] = make_float2(h[0], h[1]);
        float po[OO];
#pragma unroll
        for (int o = 0; o < OO; ++o) po[o] = th0 * wo[0][o] + th1 * wo[1][o];
#pragma unroll
        for (int s = 32; s; s >>= 1)
#pragma unroll
            for (int o = 0; o < OO; ++o) po[o] += __shfl_down(po[o], s, 64);
        __syncthreads();
        if (lane == 0)
#pragma unroll
            for (int o = 0; o < OO; ++o) ored[wave][o] = po[o];
        th[j0] = th0; th[j0 + 1] = th1;
        if (t0 < DD && t + 1 < TT) xs[t0] = x[(size_t)(b * TT + t + 1) * DD + t0];
        __syncthreads();
        if (t0 < OO) {
            float s = 0.f;
#pragma unroll
            for (int ww = 0; ww < 8; ++ww) s += ored[ww][t0];
            out_o[((size_t)b * TT + t) * OO + t0] = s;
        }
    }
}

extern "C" void kernel_launch(void* const* d_in, const int* in_sizes, int n_in,
                              void* d_out, int out_size, void* d_ws, size_t ws_size,
                              hipStream_t stream) {
    const float* x    = (const float*)d_in[0];
    const float* h0   = (const float*)d_in[1];
    const float* Wi2h = (const float*)d_in[2];
    const float* Wh2h = (const float*)d_in[3];
    const float* Wh2o = (const float*)d_in[4];

    float* out_o = (float*)d_out;                    // [64][1000][8]
    float* out_h = out_o + (size_t)BB * TT * OO;     // [64][1000][1024]

    const size_t XP_BYTES   = (size_t)BB * TT * HH * sizeof(float);            // 262 MB
    const size_t TH_BYTES   = (size_t)2 * NGRP * GB * HH * sizeof(float);      // 512 KB
    const size_t FLG1_BYTES = (size_t)2 * NGRP * 32 * 16 * sizeof(unsigned);   // 64 KB
    const size_t ID_BYTES   = (size_t)NGRP * 32 * sizeof(unsigned);            // 2 KB
    const size_t FLG2_BYTES = (size_t)2 * NGRP * 16 * 16 * sizeof(unsigned);   // 32 KB

    int occ1 = 0, occ0 = 0;
    (void)hipOccupancyMaxActiveBlocksPerMultiprocessor(
        &occ1, reinterpret_cast<const void*>(&rnn_sj32<1>), NTH, 0);
    (void)hipOccupancyMaxActiveBlocksPerMultiprocessor(
        &occ0, reinterpret_cast<const void*>(&rnn_sj32<0>), NTH, 0);

    if (ws_size >= XP_BYTES + TH_BYTES + FLG1_BYTES + ID_BYTES && occ1 >= 2) {
        float*    xp  = (float*)d_ws;
        float*    TH  = (float*)((char*)d_ws + XP_BYTES);
        unsigned* flg = (unsigned*)((char*)d_ws + XP_BYTES + TH_BYTES);
        unsigned* ids = (unsigned*)((char*)d_ws + XP_BYTES + TH_BYTES + FLG1_BYTES);
        hipMemsetAsync(flg, 0, FLG1_BYTES, stream);
        xproj_kernel<<<512, 256, 0, stream>>>(x, Wi2h, xp);
        rnn_sj32<1><<<512, NTH, 0, stream>>>(x, h0, Wi2h, Wh2h, xp, out_h, TH, flg, ids);
        h2o_kernel<<<2048, 256, 0, stream>>>(out_h, Wh2o, out_o);
    } else if (ws_size >= TH_BYTES + FLG1_BYTES + ID_BYTES && occ0 >= 2) {
        float*    TH  = (float*)d_ws;
        unsigned* flg = (unsigned*)((char*)d_ws + TH_BYTES);
        unsigned* ids = (unsigned*)((char*)d_ws + TH_BYTES + FLG1_BYTES);
        hipMemsetAsync(flg, 0, FLG1_BYTES, stream);
        rnn_sj32<0><<<512, NTH, 0, stream>>>(x, h0, Wi2h, Wh2h, (const float*)d_ws,
                                             out_h, TH, flg, ids);
        h2o_kernel<<<2048, 256, 0, stream>>>(out_h, Wh2o, out_o);
    } else if (ws_size >= TH_BYTES + FLG2_BYTES) {
        float*    TH  = (float*)d_ws;
        unsigned* flg = (unsigned*)((char*)d_ws + TH_BYTES);
        hipMemsetAsync(flg, 0, FLG2_BYTES, stream);
        rnn_coop_t2<<<256, NTH, 0, stream>>>(x, h0, Wi2h, Wh2h, out_h, TH, flg);
        h2o_kernel<<<2048, 256, 0, stream>>>(out_h, Wh2o, out_o);
    } else {
        rnn_fallback<<<BB, 512, 0, stream>>>(x, h0, Wi2h, Wh2h, Wh2o, out_o, out_h);
    }
}